// Round 5
// baseline (214.577 us; speedup 1.0000x reference)
//
#include <hip/hip_runtime.h>
#include <hip/hip_bf16.h>
#include <math.h>

// Problem constants: B=2, T=2048, M=1024, H=8, D=128
#define B_  2
#define T_  2048
#define M_  1024
#define H_  8
#define D_  128
#define NROW (B_ * T_)          // 4096
#define HD  (H_ * D_)           // 1024

#define NORM_EPS 1e-6f
#define QK_MULT  0.08838834764831845f   // sqrt(1/128)
#define ROT_BASE 10000.0f

typedef short bf16x8  __attribute__((ext_vector_type(8)));    // 8 bf16 = 4 VGPRs
typedef float f32x4   __attribute__((ext_vector_type(4)));
typedef float f32x16  __attribute__((ext_vector_type(16)));

static __device__ __forceinline__ unsigned short f2bf(float f) {
    union { __hip_bfloat16 h; unsigned short u; } cv;
    cv.h = __float2bfloat16(f);
    return cv.u;
}
static __device__ __forceinline__ float bf2f(unsigned short u) {
    union { unsigned short u; __hip_bfloat16 h; } cv;
    cv.u = u;
    return __bfloat162float(cv.h);
}
static __device__ __forceinline__ unsigned int pk2bf(float a, float b) {
    return ((unsigned int)f2bf(b) << 16) | f2bf(a);
}

// async global->LDS, 16 bytes per lane. LDS dest = wave-uniform base + lane*16.
static __device__ __forceinline__ void gload_lds16(const unsigned short* g,
                                                   unsigned short* l) {
    __builtin_amdgcn_global_load_lds(
        (const __attribute__((address_space(1))) void*)g,
        (__attribute__((address_space(3))) void*)l, 16, 0, 0);
}

// ---------------------------------------------------------------------------
// cast fp32 -> bf16, 4 elements/thread
// ---------------------------------------------------------------------------
__global__ __launch_bounds__(256) void cast_bf16(const float* __restrict__ in,
                                                 unsigned short* __restrict__ out)
{
    const int i = (blockIdx.x * 256 + threadIdx.x) * 4;
    const float4 v = *(const float4*)(in + i);
    ushort4 o;
    o.x = f2bf(v.x); o.y = f2bf(v.y); o.z = f2bf(v.z); o.w = f2bf(v.w);
    *(ushort4*)(out + i) = o;
}

// ---------------------------------------------------------------------------
// transpose + cast all 4 weights: out[n][k] = bf16(in[k][n])
// ---------------------------------------------------------------------------
__global__ __launch_bounds__(256) void transpose_cast4(const float* __restrict__ w0,
                                                       const float* __restrict__ w1,
                                                       const float* __restrict__ w2,
                                                       const float* __restrict__ w3,
                                                       unsigned short* __restrict__ wqkvT,
                                                       unsigned short* __restrict__ woT)
{
    __shared__ float t[32][33];
    const int z = blockIdx.z;
    const float* in = z == 0 ? w0 : (z == 1 ? w1 : (z == 2 ? w2 : w3));
    unsigned short* out = z < 3 ? (wqkvT + (size_t)z * 1024 * 1024) : woT;

    const int tx = threadIdx.x & 31;
    const int ty = threadIdx.x >> 5;
    const int n0 = blockIdx.x * 32;
    const int k0 = blockIdx.y * 32;
    #pragma unroll
    for (int r = 0; r < 4; ++r)
        t[ty + r * 8][tx] = in[(size_t)(k0 + ty + r * 8) * 1024 + n0 + tx];
    __syncthreads();
    #pragma unroll
    for (int r = 0; r < 4; ++r)
        out[(size_t)(n0 + ty + r * 8) * 1024 + k0 + tx] = f2bf(t[tx][ty + r * 8]);
}

// ---------------------------------------------------------------------------
// bf16 MFMA GEMM (m97 structure): C[M x N] = A[M x K] * Bt[N x K]^T, K=1024.
// MODE 0 (QKV): q,k written [b,t,h,d]; V written TRANSPOSED to vt[(b,h),d,t].
// MODE 1: fp32 out.
// ---------------------------------------------------------------------------
template <int MODE>
__global__ __launch_bounds__(256) void gemm_bt(const unsigned short* __restrict__ A,
                                               const unsigned short* __restrict__ Bt,
                                               unsigned short* __restrict__ oq,
                                               unsigned short* __restrict__ ok,
                                               unsigned short* __restrict__ vt,
                                               float* __restrict__ cf)
{
    __shared__ unsigned short As[128 * 32];
    __shared__ unsigned short Bs[128 * 32];

    const int tid  = threadIdx.x;
    const int lane = tid & 63;
    const int w    = tid >> 6;
    const int g    = lane >> 4;
    const int lc   = lane & 15;
    const int wm   = w >> 1;
    const int wn   = w & 1;

    const int m0 = blockIdx.y * 128;
    const int n0 = blockIdx.x * 128;

    const unsigned short* aBase = A  + (size_t)m0 * 1024;
    const unsigned short* bBase = Bt + (size_t)n0 * 1024;

    f32x4 acc[4][4];
    #pragma unroll
    for (int i = 0; i < 4; ++i)
        #pragma unroll
        for (int j = 0; j < 4; ++j)
            acc[i][j] = (f32x4){0.f, 0.f, 0.f, 0.f};

    for (int kt = 0; kt < 32; ++kt) {
        const int k0 = kt * 32;
        #pragma unroll
        for (int it = 0; it < 2; ++it) {
            const int u  = tid + it * 256;
            const int r2 = u >> 2;
            const int s2 = u & 3;
            gload_lds16(aBase + (size_t)r2 * 1024 + k0 + s2 * 8, &As[u * 8]);
            gload_lds16(bBase + (size_t)r2 * 1024 + k0 + s2 * 8, &Bs[u * 8]);
        }
        __syncthreads();

        bf16x8 af[4], bfr[4];
        #pragma unroll
        for (int i = 0; i < 4; ++i)
            af[i] = *(const bf16x8*)&As[(wm * 64 + i * 16 + lc) * 32 + g * 8];
        #pragma unroll
        for (int j = 0; j < 4; ++j)
            bfr[j] = *(const bf16x8*)&Bs[(wn * 64 + j * 16 + lc) * 32 + g * 8];

        #pragma unroll
        for (int i = 0; i < 4; ++i)
            #pragma unroll
            for (int j = 0; j < 4; ++j)
                acc[i][j] = __builtin_amdgcn_mfma_f32_16x16x32_bf16(af[i], bfr[j], acc[i][j], 0, 0, 0);
        __syncthreads();
    }

    if (MODE == 0) {
        const int which = n0 >> 10;
        const int ncol0 = (n0 & 1023) + wn * 64;
        if (which < 2) {
            unsigned short* outp = which == 0 ? oq : ok;
            #pragma unroll
            for (int i = 0; i < 4; ++i) {
                const int mrow = m0 + wm * 64 + i * 16 + g * 4;
                #pragma unroll
                for (int j = 0; j < 4; ++j) {
                    const int nc = ncol0 + j * 16 + lc;
                    #pragma unroll
                    for (int r = 0; r < 4; ++r)
                        outp[(size_t)(mrow + r) * 1024 + nc] = f2bf(acc[i][j][r]);
                }
            }
        } else {
            // V: write transposed -> vt[(b*8+h)*128 + d][t], packed 4x bf16
            const int b2 = m0 >> 11;
            #pragma unroll
            for (int i = 0; i < 4; ++i) {
                const int t = (m0 & 2047) + wm * 64 + i * 16 + g * 4;  // +r
                #pragma unroll
                for (int j = 0; j < 4; ++j) {
                    const int nc = ncol0 + j * 16 + lc;
                    const int hh = nc >> 7, dd = nc & 127;
                    uint2 val;
                    val.x = pk2bf(acc[i][j][0], acc[i][j][1]);
                    val.y = pk2bf(acc[i][j][2], acc[i][j][3]);
                    *(uint2*)(vt + (((size_t)(b2 * 8 + hh) * 128 + dd) * T_ + t)) = val;
                }
            }
        }
    } else {
        #pragma unroll
        for (int i = 0; i < 4; ++i) {
            const int mrow = m0 + wm * 64 + i * 16 + g * 4;
            #pragma unroll
            for (int j = 0; j < 4; ++j) {
                const int nc = n0 + wn * 64 + j * 16 + lc;
                #pragma unroll
                for (int r = 0; r < 4; ++r)
                    cf[(size_t)(mrow + r) * 1024 + nc] = acc[i][j][r];
            }
        }
    }
}

// ---------------------------------------------------------------------------
// Fused RMSNorm + RoPE + sqrt(qk_scale), bf16 in-place. 4 waves / block.
// ---------------------------------------------------------------------------
__global__ __launch_bounds__(256) void rmsnorm_rope_bf16(unsigned short* __restrict__ q,
                                                         unsigned short* __restrict__ k)
{
    const int vec = blockIdx.x * 4 + (threadIdx.x >> 6);
    unsigned short* p = (blockIdx.y == 0 ? q : k) + (size_t)vec * 128;
    const int t = (vec / H_) % T_;
    const int lane = threadIdx.x & 63;

    float e = bf2f(p[lane]);
    float o = bf2f(p[lane + 64]);
    float ss = e * e + o * o;
    #pragma unroll
    for (int off = 32; off; off >>= 1) ss += __shfl_xor(ss, off);
    const float r = rsqrtf(ss * (1.0f / 128.0f) + NORM_EPS) * QK_MULT;
    e *= r;
    o *= r;

    const float freq = expf(-(float)lane * (logf(ROT_BASE) / 64.0f));
    const float rad = (float)t * freq;
    const float c = cosf(rad);
    const float s = sinf(rad);

    p[lane]      = f2bf(e * c - o * s);
    p[lane + 64] = f2bf(e * s + o * c);
}

// ---------------------------------------------------------------------------
// Flash attention v3: 32x32x16 MFMA, S^T = K Q^T, O^T = V^T P^T.
// One 256-thr block per (b,h, q-tile 64). Wave (wj = w>>1, wq2 = w&1) owns
// q-half wq2 (32 rows), j-half wj (32 of each 64-tile).
// Fixed-shift softmax (|q|=|k|=1 after rmsnorm+scale => s in [-1,1]):
// p = exp(s), lane-local scalar lsum (lane = one q-column in S^T C-layout).
// P^T C-layout -> PV B-frags via half-wave shfl_xor(32) (no LDS round-trip).
// K/V^T staged async into XOR-swizzled LDS, double-buffered.
// Epilogue: wj=1 partials merged via LDS scratch aliased over K buffers.
// ---------------------------------------------------------------------------
__global__ __launch_bounds__(256) void flash_attn(const unsigned short* __restrict__ qb,
                                                  const unsigned short* __restrict__ kb,
                                                  const unsigned short* __restrict__ vt,
                                                  unsigned short* __restrict__ o)
{
    // pool: Ks[2][64*128] | Vs[2][128*64] | lsum scratch (64 f32)
    __shared__ __align__(16) unsigned short smem[2 * 64 * 128 + 2 * 128 * 64 + 128];
    unsigned short* KsB = smem;
    unsigned short* VsB = smem + 2 * 64 * 128;
    float* lscr = (float*)(smem + 2 * 64 * 128 + 2 * 128 * 64);
    float* scr  = (float*)smem;                    // epilogue scratch [64][129] f32

    const int tid  = threadIdx.x;
    const int lane = tid & 63;
    const int w    = tid >> 6;
    const int wj   = w >> 1;            // j-half
    const int wq2  = w & 1;             // q-half
    const int qcol = lane & 31;
    const int hi   = lane >> 5;         // half-wave

    const int bh = blockIdx.x;
    const int h  = bh & (H_ - 1);
    const int b  = bh >> 3;
    const int yy = blockIdx.y;
    const int qt = (yy & 1) ? (31 - (yy >> 1)) : (yy >> 1);
    const int q0 = qt * 64;

    const size_t bhbase  = (size_t)b * T_ * HD + (size_t)h * 128;   // q,k,o
    const size_t bhvbase = (size_t)bh * 128 * T_;                   // vt

    // staging offsets: thread stages chunks m = (w*4+it)*64 + lane
    int mI[4];
    size_t srcKoff[4], srcVoff[4];
    #pragma unroll
    for (int it = 0; it < 4; ++it) {
        const int m = (w * 4 + it) * 64 + lane;
        mI[it] = m;
        const int jK = m >> 4, cK = (m & 15) ^ (jK & 15);
        srcKoff[it] = (size_t)jK * 1024 + cK * 8;
        const int dV = m >> 3, cV = (m & 7) ^ (dV & 7);
        srcVoff[it] = (size_t)dV * T_ + cV * 8;
    }
    const unsigned short* kgb = kb + bhbase;
    const unsigned short* vgb = vt + bhvbase;

    // Q as B-operand frags: Qf[ks] = Q[q0+wq2*32+qcol][ks*16 + hi*8 .. +8]
    bf16x8 qf[8];
    {
        const unsigned short* qp = qb + bhbase + (size_t)(q0 + wq2 * 32 + qcol) * 1024 + hi * 8;
        #pragma unroll
        for (int ks = 0; ks < 8; ++ks)
            qf[ks] = *(const bf16x8*)(qp + ks * 16);
    }

    float lsum = 0.f;
    f32x16 otacc[4];
    #pragma unroll
    for (int dch = 0; dch < 4; ++dch)
        #pragma unroll
        for (int r = 0; r < 16; ++r) otacc[dch][r] = 0.f;

    // prologue: stage tile 0 into buffer 0
    #pragma unroll
    for (int it = 0; it < 4; ++it) {
        gload_lds16(kgb + srcKoff[it], &KsB[mI[it] * 8]);
        gload_lds16(vgb + srcVoff[it], &VsB[mI[it] * 8]);
    }

    for (int jt = 0; jt <= qt; ++jt) {
        const int cur = jt & 1;
        unsigned short* Ks = KsB + cur * (64 * 128);
        unsigned short* Vs = VsB + cur * (128 * 64);
        __syncthreads();

        if (jt < qt) {   // async-prefetch next tile
            const size_t j0n = (size_t)(jt + 1) * 64;
            unsigned short* Kn = KsB + (cur ^ 1) * (64 * 128);
            unsigned short* Vn = VsB + (cur ^ 1) * (128 * 64);
            #pragma unroll
            for (int it = 0; it < 4; ++it) {
                gload_lds16(kgb + j0n * 1024 + srcKoff[it], &Kn[mI[it] * 8]);
                gload_lds16(vgb + j0n + srcVoff[it], &Vn[mI[it] * 8]);
            }
        }

        const bool dead = (jt == qt) && (wj > wq2);   // wave-uniform
        if (!dead) {
            // --- S^T = K Q^T : rows j (wave's 32-half), cols q ---
            f32x16 sacc;
            #pragma unroll
            for (int r = 0; r < 16; ++r) sacc[r] = 0.f;
            const int jrow = wj * 32 + qcol;          // A-operand row
            #pragma unroll
            for (int ks = 0; ks < 8; ++ks) {
                const int c = ks * 2 + hi;            // desired 16B chunk
                bf16x8 af = *(const bf16x8*)&Ks[(jrow * 16 + (c ^ (lane & 15))) * 8];
                sacc = __builtin_amdgcn_mfma_f32_32x32x16_bf16(af, qf[ks], sacc, 0, 0, 0);
            }

            // --- causal mask (diagonal 32x32 subtile only) ---
            if (jt == qt && wj == wq2) {
                #pragma unroll
                for (int r = 0; r < 16; ++r) {
                    const int jl = (r & 3) + 8 * (r >> 2) + 4 * hi;
                    if (qcol < jl) sacc[r] = -1e30f;
                }
            }

            // --- fixed-shift softmax + pack P^T to bf16 dwords ---
            unsigned int dw[8];
            #pragma unroll
            for (int m2 = 0; m2 < 8; ++m2) {
                const float p0 = __expf(sacc[2 * m2]);
                const float p1 = __expf(sacc[2 * m2 + 1]);
                lsum += p0 + p1;
                dw[m2] = pk2bf(p0, p1);
            }
            unsigned int ex[8];
            #pragma unroll
            for (int m2 = 0; m2 < 8; ++m2)
                ex[m2] = (unsigned int)__shfl_xor((int)dw[m2], 32);

            // --- O^T += V^T P^T ---
            #pragma unroll
            for (int ks2 = 0; ks2 < 2; ++ks2) {
                union { unsigned int u[4]; bf16x8 v; } pf;
                pf.u[0] = hi ? ex[4 * ks2 + 2] : dw[4 * ks2 + 0];
                pf.u[1] = hi ? ex[4 * ks2 + 3] : dw[4 * ks2 + 1];
                pf.u[2] = hi ? dw[4 * ks2 + 2] : ex[4 * ks2 + 0];
                pf.u[3] = hi ? dw[4 * ks2 + 3] : ex[4 * ks2 + 1];
                #pragma unroll
                for (int dch = 0; dch < 4; ++dch) {
                    const int c = wj * 4 + ks2 * 2 + hi;   // desired chunk in Vs row
                    const int drow = dch * 32 + qcol;
                    bf16x8 af = *(const bf16x8*)&Vs[(drow * 8 + (c ^ (lane & 7))) * 8];
                    otacc[dch] = __builtin_amdgcn_mfma_f32_32x32x16_bf16(af, pf.v, otacc[dch], 0, 0, 0);
                }
            }
        }
    }

    // --- epilogue: merge wj pairs via LDS, write O bf16 ---
    lsum += __shfl_xor(lsum, 32);                  // combine half-waves (per q)
    __syncthreads();                               // K/V buffers now dead

    if (wj == 1) {
        float* s0 = scr + (size_t)(wq2 * 32 + qcol) * 129;
        #pragma unroll
        for (int dch = 0; dch < 4; ++dch)
            #pragma unroll
            for (int r = 0; r < 16; ++r)
                s0[dch * 32 + (r & 3) + 8 * (r >> 2) + 4 * hi] = otacc[dch][r];
        if (hi == 0) lscr[wq2 * 32 + qcol] = lsum;
    }
    __syncthreads();
    if (wj == 0) {
        const float l = lsum + lscr[wq2 * 32 + qcol];
        const float inv = 1.0f / l;
        const float* s0 = scr + (size_t)(wq2 * 32 + qcol) * 129;
        unsigned short* op = o + bhbase + (size_t)(q0 + wq2 * 32 + qcol) * 1024;
        #pragma unroll
        for (int dch = 0; dch < 4; ++dch) {
            #pragma unroll
            for (int k4 = 0; k4 < 4; ++k4) {
                const int d0 = dch * 32 + 8 * k4 + 4 * hi;
                const float f0 = (otacc[dch][4 * k4 + 0] + s0[d0 + 0]) * inv;
                const float f1 = (otacc[dch][4 * k4 + 1] + s0[d0 + 1]) * inv;
                const float f2 = (otacc[dch][4 * k4 + 2] + s0[d0 + 2]) * inv;
                const float f3 = (otacc[dch][4 * k4 + 3] + s0[d0 + 3]) * inv;
                uint2 val;
                val.x = pk2bf(f0, f1);
                val.y = pk2bf(f2, f3);
                *(uint2*)(op + d0) = val;
            }
        }
    }
}

// ---------------------------------------------------------------------------
extern "C" void kernel_launch(void* const* d_in, const int* in_sizes, int n_in,
                              void* d_out, int out_size, void* d_ws, size_t ws_size,
                              hipStream_t stream)
{
    const float* x  = (const float*)d_in[0];
    const float* wq = (const float*)d_in[1];
    const float* wk = (const float*)d_in[2];
    const float* wv = (const float*)d_in[3];
    const float* wo = (const float*)d_in[4];
    float* out = (float*)d_out;

    const size_t SZ = (size_t)NROW * HD;               // 4M elements
    unsigned short* qb    = (unsigned short*)d_ws;     // 8 MB
    unsigned short* kb    = qb + SZ;                   // 8 MB
    unsigned short* vt    = kb + SZ;                   // 8 MB [(b,h),d,t]
    unsigned short* ob    = vt + SZ;                   // 8 MB
    unsigned short* xb    = ob + SZ;                   // 8 MB
    unsigned short* wqkvT = xb + SZ;                   // 6 MB [3072][1024]
    unsigned short* woT   = wqkvT + 3 * 1024 * 1024;   // 2 MB

    cast_bf16<<<SZ / (256 * 4), 256, 0, stream>>>(x, xb);
    transpose_cast4<<<dim3(32, 32, 4), 256, 0, stream>>>(wq, wk, wv, wo, wqkvT, woT);

    // fused QKV projection (V written transposed into vt)
    gemm_bt<0><<<dim3(24, 32), 256, 0, stream>>>(xb, wqkvT, qb, kb, vt, nullptr);

    rmsnorm_rope_bf16<<<dim3(NROW * H_ / 4, 2), 256, 0, stream>>>(qb, kb);

    flash_attn<<<dim3(B_ * H_, 32), 256, 0, stream>>>(qb, kb, vt, ob);

    gemm_bt<1><<<dim3(8, 32), 256, 0, stream>>>(ob, woT, nullptr, nullptr, nullptr, out);
}

// Round 6
// 203.682 us; speedup vs baseline: 1.0535x; 1.0535x over previous
//
#include <hip/hip_runtime.h>
#include <hip/hip_bf16.h>
#include <math.h>

// Problem constants: B=2, T=2048, M=1024, H=8, D=128
#define B_  2
#define T_  2048
#define M_  1024
#define H_  8
#define D_  128
#define NROW (B_ * T_)          // 4096
#define HD  (H_ * D_)           // 1024

#define NORM_EPS 1e-6f
#define QK_MULT  0.08838834764831845f   // sqrt(1/128)
#define LN_BASE_64 0.14391156510f       // ln(10000)/64

typedef short bf16x8  __attribute__((ext_vector_type(8)));    // 8 bf16 = 4 VGPRs
typedef float f32x4   __attribute__((ext_vector_type(4)));
typedef float f32x16  __attribute__((ext_vector_type(16)));

static __device__ __forceinline__ unsigned short f2bf(float f) {
    union { __hip_bfloat16 h; unsigned short u; } cv;
    cv.h = __float2bfloat16(f);
    return cv.u;
}
static __device__ __forceinline__ float bf2f(unsigned short u) {
    union { unsigned short u; __hip_bfloat16 h; } cv;
    cv.u = u;
    return __bfloat162float(cv.h);
}
static __device__ __forceinline__ unsigned int pk2bf(float a, float b) {
    return ((unsigned int)f2bf(b) << 16) | f2bf(a);
}

// async global->LDS, 16 bytes per lane. LDS dest = wave-uniform base + lane*16.
static __device__ __forceinline__ void gload_lds16(const unsigned short* g,
                                                   unsigned short* l) {
    __builtin_amdgcn_global_load_lds(
        (const __attribute__((address_space(1))) void*)g,
        (__attribute__((address_space(3))) void*)l, 16, 0, 0);
}

// ---------------------------------------------------------------------------
// prep: z<4 -> transpose+cast weight z (out[n][k]=bf16(in[k][n]));
//       z==4 -> linear cast of x to bf16.
// ---------------------------------------------------------------------------
__global__ __launch_bounds__(256) void prep(const float* __restrict__ x,
                                            const float* __restrict__ w0,
                                            const float* __restrict__ w1,
                                            const float* __restrict__ w2,
                                            const float* __restrict__ w3,
                                            unsigned short* __restrict__ xb,
                                            unsigned short* __restrict__ wqkvT,
                                            unsigned short* __restrict__ woT)
{
    __shared__ float t[32][33];
    const int z = blockIdx.z;
    if (z == 4) {
        const size_t base = ((size_t)blockIdx.y * 32 + blockIdx.x) * 4096;
        #pragma unroll
        for (int it = 0; it < 4; ++it) {
            const size_t i = base + it * 1024 + threadIdx.x * 4;
            const float4 v = *(const float4*)(x + i);
            ushort4 o;
            o.x = f2bf(v.x); o.y = f2bf(v.y); o.z = f2bf(v.z); o.w = f2bf(v.w);
            *(ushort4*)(xb + i) = o;
        }
        return;
    }
    const float* in = z == 0 ? w0 : (z == 1 ? w1 : (z == 2 ? w2 : w3));
    unsigned short* out = z < 3 ? (wqkvT + (size_t)z * 1024 * 1024) : woT;

    const int tx = threadIdx.x & 31;
    const int ty = threadIdx.x >> 5;
    const int n0 = blockIdx.x * 32;
    const int k0 = blockIdx.y * 32;
    #pragma unroll
    for (int r = 0; r < 4; ++r)
        t[ty + r * 8][tx] = in[(size_t)(k0 + ty + r * 8) * 1024 + n0 + tx];
    __syncthreads();
    #pragma unroll
    for (int r = 0; r < 4; ++r)
        out[(size_t)(n0 + ty + r * 8) * 1024 + k0 + tx] = f2bf(t[tx][ty + r * 8]);
}

// ---------------------------------------------------------------------------
// bf16 MFMA GEMM (m97 structure): C[M x N] = A[M x K] * Bt[N x K]^T, K=1024.
// MODE 0 (QKV): q,k get FUSED RMSNorm+RoPE+scale in the epilogue (a block's
//   128-col extent is exactly one head), written [b,t,h,d];
//   V written TRANSPOSED to vt[(b,h),d,t].
// MODE 1: fp32 out.
// LDS pool: loop uses As/Bs (16 KB); epilogue (which<2) aliases a 34 KB
// xbuf (stride 132 -> 2-way conflict = free) + sq scratch over it.
// ---------------------------------------------------------------------------
template <int MODE>
__global__ __launch_bounds__(256) void gemm_bt(const unsigned short* __restrict__ A,
                                               const unsigned short* __restrict__ Bt,
                                               unsigned short* __restrict__ oq,
                                               unsigned short* __restrict__ ok,
                                               unsigned short* __restrict__ vt,
                                               float* __restrict__ cf)
{
    __shared__ __align__(16) unsigned short pool[128 * 132 + 512];
    unsigned short* As = pool;                    // [128][32]
    unsigned short* Bs = pool + 128 * 32;         // [128][32]

    const int tid  = threadIdx.x;
    const int lane = tid & 63;
    const int w    = tid >> 6;
    const int g    = lane >> 4;
    const int lc   = lane & 15;
    const int wm   = w >> 1;
    const int wn   = w & 1;

    const int m0 = blockIdx.y * 128;
    const int n0 = blockIdx.x * 128;

    const unsigned short* aBase = A  + (size_t)m0 * 1024;
    const unsigned short* bBase = Bt + (size_t)n0 * 1024;

    f32x4 acc[4][4];
    #pragma unroll
    for (int i = 0; i < 4; ++i)
        #pragma unroll
        for (int j = 0; j < 4; ++j)
            acc[i][j] = (f32x4){0.f, 0.f, 0.f, 0.f};

    for (int kt = 0; kt < 32; ++kt) {
        const int k0 = kt * 32;
        #pragma unroll
        for (int it = 0; it < 2; ++it) {
            const int u  = tid + it * 256;
            const int r2 = u >> 2;
            const int s2 = u & 3;
            gload_lds16(aBase + (size_t)r2 * 1024 + k0 + s2 * 8, &As[u * 8]);
            gload_lds16(bBase + (size_t)r2 * 1024 + k0 + s2 * 8, &Bs[u * 8]);
        }
        __syncthreads();

        bf16x8 af[4], bfr[4];
        #pragma unroll
        for (int i = 0; i < 4; ++i)
            af[i] = *(const bf16x8*)&As[(wm * 64 + i * 16 + lc) * 32 + g * 8];
        #pragma unroll
        for (int j = 0; j < 4; ++j)
            bfr[j] = *(const bf16x8*)&Bs[(wn * 64 + j * 16 + lc) * 32 + g * 8];

        #pragma unroll
        for (int i = 0; i < 4; ++i)
            #pragma unroll
            for (int j = 0; j < 4; ++j)
                acc[i][j] = __builtin_amdgcn_mfma_f32_16x16x32_bf16(af[i], bfr[j], acc[i][j], 0, 0, 0);
        __syncthreads();
    }

    if (MODE == 0) {
        const int which = n0 >> 10;
        const int ncol0 = (n0 & 1023) + wn * 64;
        if (which < 2) {
            // ---- fused RMSNorm + RoPE + sqrt(qk_scale) for q / k ----
            unsigned short* outp = which == 0 ? oq : ok;
            unsigned short* xbuf = pool;                        // [128][132] bf16
            float* sqbuf = (float*)(pool + 128 * 132);          // [2][128]

            // 1. per-row sum of squares over this wave's 64-col half
            float sq[4][4];
            #pragma unroll
            for (int i = 0; i < 4; ++i)
                #pragma unroll
                for (int r = 0; r < 4; ++r) {
                    float s = acc[i][0][r] * acc[i][0][r] + acc[i][1][r] * acc[i][1][r]
                            + acc[i][2][r] * acc[i][2][r] + acc[i][3][r] * acc[i][3][r];
                    #pragma unroll
                    for (int off = 1; off < 16; off <<= 1) s += __shfl_xor(s, off);
                    sq[i][r] = s;
                }
            if (lc == 0) {
                #pragma unroll
                for (int i = 0; i < 4; ++i)
                    #pragma unroll
                    for (int r = 0; r < 4; ++r)
                        sqbuf[wn * 128 + wm * 64 + i * 16 + g * 4 + r] = sq[i][r];
            }
            __syncthreads();

            // 2. normalize (keep f32 in regs), stash bf16 to xbuf for pair exch
            #pragma unroll
            for (int i = 0; i < 4; ++i)
                #pragma unroll
                for (int r = 0; r < 4; ++r) {
                    const int row = wm * 64 + i * 16 + g * 4 + r;
                    const float tot = sqbuf[row] + sqbuf[128 + row];
                    const float rms = rsqrtf(tot * (1.0f / 128.0f) + NORM_EPS) * QK_MULT;
                    #pragma unroll
                    for (int j = 0; j < 4; ++j) {
                        acc[i][j][r] *= rms;
                        xbuf[row * 132 + wn * 64 + j * 16 + lc] = f2bf(acc[i][j][r]);
                    }
                }
            __syncthreads();

            // 3. RoPE pair combine + store
            float freq[4];
            #pragma unroll
            for (int j = 0; j < 4; ++j)
                freq[j] = __expf(-(float)(j * 16 + lc) * LN_BASE_64);
            #pragma unroll
            for (int i = 0; i < 4; ++i)
                #pragma unroll
                for (int r = 0; r < 4; ++r) {
                    const int row  = wm * 64 + i * 16 + g * 4 + r;
                    const int trow = m0 + row;
                    const float tpos = (float)(trow & (T_ - 1));
                    #pragma unroll
                    for (int j = 0; j < 4; ++j) {
                        float sn, cs;
                        __sincosf(tpos * freq[j], &sn, &cs);
                        const float own = acc[i][j][r];
                        const float par = bf2f(xbuf[row * 132 + ((wn ^ 1) * 64) + j * 16 + lc]);
                        const float outv = (wn == 0) ? (own * cs - par * sn)   // even: e*c - o*s
                                                     : (par * sn + own * cs);  // odd:  e*s + o*c
                        outp[(size_t)trow * 1024 + ncol0 + j * 16 + lc] = f2bf(outv);
                    }
                }
        } else {
            // V: write transposed -> vt[(b*8+h)*128 + d][t], packed 4x bf16
            const int b2 = m0 >> 11;
            #pragma unroll
            for (int i = 0; i < 4; ++i) {
                const int t = (m0 & 2047) + wm * 64 + i * 16 + g * 4;  // +r
                #pragma unroll
                for (int j = 0; j < 4; ++j) {
                    const int nc = ncol0 + j * 16 + lc;
                    const int hh = nc >> 7, dd = nc & 127;
                    uint2 val;
                    val.x = pk2bf(acc[i][j][0], acc[i][j][1]);
                    val.y = pk2bf(acc[i][j][2], acc[i][j][3]);
                    *(uint2*)(vt + (((size_t)(b2 * 8 + hh) * 128 + dd) * T_ + t)) = val;
                }
            }
        }
    } else {
        #pragma unroll
        for (int i = 0; i < 4; ++i) {
            const int mrow = m0 + wm * 64 + i * 16 + g * 4;
            #pragma unroll
            for (int j = 0; j < 4; ++j) {
                const int nc = n0 + wn * 64 + j * 16 + lc;
                #pragma unroll
                for (int r = 0; r < 4; ++r)
                    cf[(size_t)(mrow + r) * 1024 + nc] = acc[i][j][r];
            }
        }
    }
}

// ---------------------------------------------------------------------------
// Flash attention v3: 32x32x16 MFMA, S^T = K Q^T, O^T = V^T P^T.
// One 256-thr block per (b,h, q-tile 64). Wave (wj = w>>1, wq2 = w&1) owns
// q-half wq2 (32 rows), j-half wj (32 of each 64-tile).
// Fixed-shift softmax (|q|=|k|=1 after rmsnorm+scale => s in [-1,1]):
// p = exp(s), lane-local scalar lsum. P^T C-layout -> PV B-frags via
// half-wave shfl_xor(32). K/V^T staged async into XOR-swizzled LDS, dbuf.
// ---------------------------------------------------------------------------
__global__ __launch_bounds__(256) void flash_attn(const unsigned short* __restrict__ qb,
                                                  const unsigned short* __restrict__ kb,
                                                  const unsigned short* __restrict__ vt,
                                                  unsigned short* __restrict__ o)
{
    __shared__ __align__(16) unsigned short smem[2 * 64 * 128 + 2 * 128 * 64 + 128];
    unsigned short* KsB = smem;
    unsigned short* VsB = smem + 2 * 64 * 128;
    float* lscr = (float*)(smem + 2 * 64 * 128 + 2 * 128 * 64);
    float* scr  = (float*)smem;                    // epilogue scratch [64][129] f32

    const int tid  = threadIdx.x;
    const int lane = tid & 63;
    const int w    = tid >> 6;
    const int wj   = w >> 1;            // j-half
    const int wq2  = w & 1;             // q-half
    const int qcol = lane & 31;
    const int hi   = lane >> 5;         // half-wave

    const int bh = blockIdx.x;
    const int h  = bh & (H_ - 1);
    const int b  = bh >> 3;
    const int yy = blockIdx.y;
    const int qt = (yy & 1) ? (31 - (yy >> 1)) : (yy >> 1);
    const int q0 = qt * 64;

    const size_t bhbase  = (size_t)b * T_ * HD + (size_t)h * 128;   // q,k,o
    const size_t bhvbase = (size_t)bh * 128 * T_;                   // vt

    int mI[4];
    size_t srcKoff[4], srcVoff[4];
    #pragma unroll
    for (int it = 0; it < 4; ++it) {
        const int m = (w * 4 + it) * 64 + lane;
        mI[it] = m;
        const int jK = m >> 4, cK = (m & 15) ^ (jK & 15);
        srcKoff[it] = (size_t)jK * 1024 + cK * 8;
        const int dV = m >> 3, cV = (m & 7) ^ (dV & 7);
        srcVoff[it] = (size_t)dV * T_ + cV * 8;
    }
    const unsigned short* kgb = kb + bhbase;
    const unsigned short* vgb = vt + bhvbase;

    // Q as B-operand frags
    bf16x8 qf[8];
    {
        const unsigned short* qp = qb + bhbase + (size_t)(q0 + wq2 * 32 + qcol) * 1024 + hi * 8;
        #pragma unroll
        for (int ks = 0; ks < 8; ++ks)
            qf[ks] = *(const bf16x8*)(qp + ks * 16);
    }

    float lsum = 0.f;
    f32x16 otacc[4];
    #pragma unroll
    for (int dch = 0; dch < 4; ++dch)
        #pragma unroll
        for (int r = 0; r < 16; ++r) otacc[dch][r] = 0.f;

    #pragma unroll
    for (int it = 0; it < 4; ++it) {
        gload_lds16(kgb + srcKoff[it], &KsB[mI[it] * 8]);
        gload_lds16(vgb + srcVoff[it], &VsB[mI[it] * 8]);
    }

    for (int jt = 0; jt <= qt; ++jt) {
        const int cur = jt & 1;
        unsigned short* Ks = KsB + cur * (64 * 128);
        unsigned short* Vs = VsB + cur * (128 * 64);
        __syncthreads();

        if (jt < qt) {
            const size_t j0n = (size_t)(jt + 1) * 64;
            unsigned short* Kn = KsB + (cur ^ 1) * (64 * 128);
            unsigned short* Vn = VsB + (cur ^ 1) * (128 * 64);
            #pragma unroll
            for (int it = 0; it < 4; ++it) {
                gload_lds16(kgb + j0n * 1024 + srcKoff[it], &Kn[mI[it] * 8]);
                gload_lds16(vgb + j0n + srcVoff[it], &Vn[mI[it] * 8]);
            }
        }

        const bool dead = (jt == qt) && (wj > wq2);
        if (!dead) {
            f32x16 sacc;
            #pragma unroll
            for (int r = 0; r < 16; ++r) sacc[r] = 0.f;
            const int jrow = wj * 32 + qcol;
            #pragma unroll
            for (int ks = 0; ks < 8; ++ks) {
                const int c = ks * 2 + hi;
                bf16x8 af = *(const bf16x8*)&Ks[(jrow * 16 + (c ^ (lane & 15))) * 8];
                sacc = __builtin_amdgcn_mfma_f32_32x32x16_bf16(af, qf[ks], sacc, 0, 0, 0);
            }

            if (jt == qt && wj == wq2) {
                #pragma unroll
                for (int r = 0; r < 16; ++r) {
                    const int jl = (r & 3) + 8 * (r >> 2) + 4 * hi;
                    if (qcol < jl) sacc[r] = -1e30f;
                }
            }

            unsigned int dw[8];
            #pragma unroll
            for (int m2 = 0; m2 < 8; ++m2) {
                const float p0 = __expf(sacc[2 * m2]);
                const float p1 = __expf(sacc[2 * m2 + 1]);
                lsum += p0 + p1;
                dw[m2] = pk2bf(p0, p1);
            }
            unsigned int ex[8];
            #pragma unroll
            for (int m2 = 0; m2 < 8; ++m2)
                ex[m2] = (unsigned int)__shfl_xor((int)dw[m2], 32);

            #pragma unroll
            for (int ks2 = 0; ks2 < 2; ++ks2) {
                union { unsigned int u[4]; bf16x8 v; } pf;
                pf.u[0] = hi ? ex[4 * ks2 + 2] : dw[4 * ks2 + 0];
                pf.u[1] = hi ? ex[4 * ks2 + 3] : dw[4 * ks2 + 1];
                pf.u[2] = hi ? dw[4 * ks2 + 2] : ex[4 * ks2 + 0];
                pf.u[3] = hi ? dw[4 * ks2 + 3] : ex[4 * ks2 + 1];
                #pragma unroll
                for (int dch = 0; dch < 4; ++dch) {
                    const int c = wj * 4 + ks2 * 2 + hi;
                    const int drow = dch * 32 + qcol;
                    bf16x8 af = *(const bf16x8*)&Vs[(drow * 8 + (c ^ (lane & 7))) * 8];
                    otacc[dch] = __builtin_amdgcn_mfma_f32_32x32x16_bf16(af, pf.v, otacc[dch], 0, 0, 0);
                }
            }
        }
    }

    // epilogue: merge wj pairs via LDS, write O bf16
    lsum += __shfl_xor(lsum, 32);
    __syncthreads();

    if (wj == 1) {
        float* s0 = scr + (size_t)(wq2 * 32 + qcol) * 129;
        #pragma unroll
        for (int dch = 0; dch < 4; ++dch)
            #pragma unroll
            for (int r = 0; r < 16; ++r)
                s0[dch * 32 + (r & 3) + 8 * (r >> 2) + 4 * hi] = otacc[dch][r];
        if (hi == 0) lscr[wq2 * 32 + qcol] = lsum;
    }
    __syncthreads();
    if (wj == 0) {
        const float l = lsum + lscr[wq2 * 32 + qcol];
        const float inv = 1.0f / l;
        const float* s0 = scr + (size_t)(wq2 * 32 + qcol) * 129;
        unsigned short* op = o + bhbase + (size_t)(q0 + wq2 * 32 + qcol) * 1024;
        #pragma unroll
        for (int dch = 0; dch < 4; ++dch) {
            #pragma unroll
            for (int k4 = 0; k4 < 4; ++k4) {
                const int d0 = dch * 32 + 8 * k4 + 4 * hi;
                const float f0 = (otacc[dch][4 * k4 + 0] + s0[d0 + 0]) * inv;
                const float f1 = (otacc[dch][4 * k4 + 1] + s0[d0 + 1]) * inv;
                const float f2 = (otacc[dch][4 * k4 + 2] + s0[d0 + 2]) * inv;
                const float f3 = (otacc[dch][4 * k4 + 3] + s0[d0 + 3]) * inv;
                uint2 val;
                val.x = pk2bf(f0, f1);
                val.y = pk2bf(f2, f3);
                *(uint2*)(op + d0) = val;
            }
        }
    }
}

// ---------------------------------------------------------------------------
extern "C" void kernel_launch(void* const* d_in, const int* in_sizes, int n_in,
                              void* d_out, int out_size, void* d_ws, size_t ws_size,
                              hipStream_t stream)
{
    const float* x  = (const float*)d_in[0];
    const float* wq = (const float*)d_in[1];
    const float* wk = (const float*)d_in[2];
    const float* wv = (const float*)d_in[3];
    const float* wo = (const float*)d_in[4];
    float* out = (float*)d_out;

    const size_t SZ = (size_t)NROW * HD;               // 4M elements
    unsigned short* qb    = (unsigned short*)d_ws;     // 8 MB
    unsigned short* kb    = qb + SZ;                   // 8 MB
    unsigned short* vt    = kb + SZ;                   // 8 MB [(b,h),d,t]
    unsigned short* ob    = vt + SZ;                   // 8 MB
    unsigned short* xb    = ob + SZ;                   // 8 MB
    unsigned short* wqkvT = xb + SZ;                   // 6 MB [3072][1024]
    unsigned short* woT   = wqkvT + 3 * 1024 * 1024;   // 2 MB

    // prologue: x cast + 4 weight transposes, one launch
    prep<<<dim3(32, 32, 5), 256, 0, stream>>>(x, wq, wk, wv, wo, xb, wqkvT, woT);

    // fused QKV projection (+ RMSNorm/RoPE on q,k; V written transposed)
    gemm_bt<0><<<dim3(24, 32), 256, 0, stream>>>(xb, wqkvT, qb, kb, vt, nullptr);

    flash_attn<<<dim3(B_ * H_, 32), 256, 0, stream>>>(qb, kb, vt, ob);

    gemm_bt<1><<<dim3(8, 32), 256, 0, stream>>>(ob, woT, nullptr, nullptr, nullptr, out);
}

// Round 7
// 196.162 us; speedup vs baseline: 1.0939x; 1.0383x over previous
//
#include <hip/hip_runtime.h>
#include <hip/hip_bf16.h>
#include <math.h>

// Problem constants: B=2, T=2048, M=1024, H=8, D=128
#define B_  2
#define T_  2048
#define M_  1024
#define H_  8
#define D_  128
#define NROW (B_ * T_)          // 4096
#define HD  (H_ * D_)           // 1024

#define NORM_EPS 1e-6f
#define QK_MULT  0.08838834764831845f   // sqrt(1/128)
#define LN_BASE_64 0.14391156510f       // ln(10000)/64

typedef short bf16x8  __attribute__((ext_vector_type(8)));    // 8 bf16 = 4 VGPRs
typedef float f32x4   __attribute__((ext_vector_type(4)));
typedef float f32x16  __attribute__((ext_vector_type(16)));

static __device__ __forceinline__ unsigned short f2bf(float f) {
    union { __hip_bfloat16 h; unsigned short u; } cv;
    cv.h = __float2bfloat16(f);
    return cv.u;
}
static __device__ __forceinline__ float bf2f(unsigned short u) {
    union { unsigned short u; __hip_bfloat16 h; } cv;
    cv.u = u;
    return __bfloat162float(cv.h);
}
static __device__ __forceinline__ unsigned int pk2bf(float a, float b) {
    return ((unsigned int)f2bf(b) << 16) | f2bf(a);
}

// async global->LDS, 16 bytes per lane. LDS dest = wave-uniform base + lane*16.
static __device__ __forceinline__ void gload_lds16(const unsigned short* g,
                                                   unsigned short* l) {
    __builtin_amdgcn_global_load_lds(
        (const __attribute__((address_space(1))) void*)g,
        (__attribute__((address_space(3))) void*)l, 16, 0, 0);
}

// ---------------------------------------------------------------------------
// prep: z<4 -> transpose+cast weight z (out[n][k]=bf16(in[k][n]));
//       z==4 -> linear cast of x to bf16.
// ---------------------------------------------------------------------------
__global__ __launch_bounds__(256) void prep(const float* __restrict__ x,
                                            const float* __restrict__ w0,
                                            const float* __restrict__ w1,
                                            const float* __restrict__ w2,
                                            const float* __restrict__ w3,
                                            unsigned short* __restrict__ xb,
                                            unsigned short* __restrict__ wqkvT,
                                            unsigned short* __restrict__ woT)
{
    __shared__ float t[32][33];
    const int z = blockIdx.z;
    if (z == 4) {
        const size_t base = ((size_t)blockIdx.y * 32 + blockIdx.x) * 4096;
        #pragma unroll
        for (int it = 0; it < 4; ++it) {
            const size_t i = base + it * 1024 + threadIdx.x * 4;
            const float4 v = *(const float4*)(x + i);
            ushort4 o;
            o.x = f2bf(v.x); o.y = f2bf(v.y); o.z = f2bf(v.z); o.w = f2bf(v.w);
            *(ushort4*)(xb + i) = o;
        }
        return;
    }
    const float* in = z == 0 ? w0 : (z == 1 ? w1 : (z == 2 ? w2 : w3));
    unsigned short* out = z < 3 ? (wqkvT + (size_t)z * 1024 * 1024) : woT;

    const int tx = threadIdx.x & 31;
    const int ty = threadIdx.x >> 5;
    const int n0 = blockIdx.x * 32;
    const int k0 = blockIdx.y * 32;
    #pragma unroll
    for (int r = 0; r < 4; ++r)
        t[ty + r * 8][tx] = in[(size_t)(k0 + ty + r * 8) * 1024 + n0 + tx];
    __syncthreads();
    #pragma unroll
    for (int r = 0; r < 4; ++r)
        out[(size_t)(n0 + ty + r * 8) * 1024 + k0 + tx] = f2bf(t[tx][ty + r * 8]);
}

// ---------------------------------------------------------------------------
// QKV GEMM (m97 structure, 4x1 wave layout): C = A[4096x1024] * Bt^T.
// Each wave owns 32 rows x ALL 128 cols (i<2 row-frags, j<8 col-frags) so
// the RoPE pair (d, d+64) = (acc j, acc j+4) is register-local: the fused
// RMSNorm+RoPE epilogue needs NO LDS exchange and NO extra barriers.
// q,k: fused norm+rope, written [b,t,h,d]. V: written transposed to
// vt[(b,h),d,t].
// ---------------------------------------------------------------------------
__global__ __launch_bounds__(256) void gemm_qkv(const unsigned short* __restrict__ A,
                                                const unsigned short* __restrict__ Bt,
                                                unsigned short* __restrict__ oq,
                                                unsigned short* __restrict__ ok,
                                                unsigned short* __restrict__ vt)
{
    __shared__ unsigned short As[128 * 32];
    __shared__ unsigned short Bs[128 * 32];

    const int tid  = threadIdx.x;
    const int lane = tid & 63;
    const int w    = tid >> 6;          // wave = row band (32 rows)
    const int g    = lane >> 4;
    const int lc   = lane & 15;

    const int m0 = blockIdx.y * 128;
    const int n0 = blockIdx.x * 128;

    const unsigned short* aBase = A  + (size_t)m0 * 1024;
    const unsigned short* bBase = Bt + (size_t)n0 * 1024;

    f32x4 acc[2][8];
    #pragma unroll
    for (int i = 0; i < 2; ++i)
        #pragma unroll
        for (int j = 0; j < 8; ++j)
            acc[i][j] = (f32x4){0.f, 0.f, 0.f, 0.f};

    for (int kt = 0; kt < 32; ++kt) {
        const int k0 = kt * 32;
        #pragma unroll
        for (int it = 0; it < 2; ++it) {
            const int u  = tid + it * 256;
            const int r2 = u >> 2;
            const int s2 = u & 3;
            gload_lds16(aBase + (size_t)r2 * 1024 + k0 + s2 * 8, &As[u * 8]);
            gload_lds16(bBase + (size_t)r2 * 1024 + k0 + s2 * 8, &Bs[u * 8]);
        }
        __syncthreads();

        bf16x8 af[2], bfr[8];
        #pragma unroll
        for (int i = 0; i < 2; ++i)
            af[i] = *(const bf16x8*)&As[(w * 32 + i * 16 + lc) * 32 + g * 8];
        #pragma unroll
        for (int j = 0; j < 8; ++j)
            bfr[j] = *(const bf16x8*)&Bs[(j * 16 + lc) * 32 + g * 8];

        #pragma unroll
        for (int i = 0; i < 2; ++i)
            #pragma unroll
            for (int j = 0; j < 8; ++j)
                acc[i][j] = __builtin_amdgcn_mfma_f32_16x16x32_bf16(af[i], bfr[j], acc[i][j], 0, 0, 0);
        __syncthreads();
    }

    const int which = n0 >> 10;
    const int ncol0 = n0 & 1023;            // head-aligned (tile = one head)
    if (which < 2) {
        // ---- fused RMSNorm + RoPE + sqrt(qk_scale) for q / k ----
        unsigned short* outp = which == 0 ? oq : ok;
        float freq[4];
        #pragma unroll
        for (int j = 0; j < 4; ++j)
            freq[j] = __expf(-(float)(j * 16 + lc) * LN_BASE_64);

        #pragma unroll
        for (int i = 0; i < 2; ++i)
            #pragma unroll
            for (int r = 0; r < 4; ++r) {
                // full-row sum of squares (all 128 cols in this wave)
                float s = 0.f;
                #pragma unroll
                for (int j = 0; j < 8; ++j) s += acc[i][j][r] * acc[i][j][r];
                #pragma unroll
                for (int off = 1; off < 16; off <<= 1) s += __shfl_xor(s, off);
                const float rms = rsqrtf(s * (1.0f / 128.0f) + NORM_EPS) * QK_MULT;

                const int trow = m0 + w * 32 + i * 16 + g * 4 + r;
                const float tpos = (float)(trow & (T_ - 1));
                unsigned short* op = outp + (size_t)trow * 1024 + ncol0;
                #pragma unroll
                for (int j = 0; j < 4; ++j) {
                    float sn, cs;
                    __sincosf(tpos * freq[j], &sn, &cs);
                    const float e = acc[i][j][r] * rms;       // even half: col j*16+lc
                    const float o = acc[i][j + 4][r] * rms;   // odd half:  +64
                    op[j * 16 + lc]      = f2bf(e * cs - o * sn);
                    op[j * 16 + lc + 64] = f2bf(e * sn + o * cs);
                }
            }
    } else {
        // V: write transposed -> vt[(b*8+h)*128 + d][t], packed 4x bf16
        const int b2 = m0 >> 11;
        const int hh = ncol0 >> 7;
        #pragma unroll
        for (int i = 0; i < 2; ++i) {
            const int t = (m0 & 2047) + w * 32 + i * 16 + g * 4;  // +r
            #pragma unroll
            for (int j = 0; j < 8; ++j) {
                const int dd = j * 16 + lc;
                uint2 val;
                val.x = pk2bf(acc[i][j][0], acc[i][j][1]);
                val.y = pk2bf(acc[i][j][2], acc[i][j][3]);
                *(uint2*)(vt + (((size_t)(b2 * 8 + hh) * 128 + dd) * T_ + t)) = val;
            }
        }
    }
}

// ---------------------------------------------------------------------------
// Output projection: C[4096x1024] fp32 = A[4096x1024] * Bt[1024x1024]^T.
// 128x64 tile -> 512 blocks (2/CU) for latency hiding. 2x2 waves of 64x32.
// ---------------------------------------------------------------------------
__global__ __launch_bounds__(256) void gemm_out(const unsigned short* __restrict__ A,
                                                const unsigned short* __restrict__ Bt,
                                                float* __restrict__ cf)
{
    __shared__ unsigned short As[128 * 32];
    __shared__ unsigned short Bs[64 * 32];

    const int tid  = threadIdx.x;
    const int lane = tid & 63;
    const int w    = tid >> 6;
    const int g    = lane >> 4;
    const int lc   = lane & 15;
    const int wm   = w >> 1;
    const int wn   = w & 1;

    const int m0 = blockIdx.y * 128;
    const int n0 = blockIdx.x * 64;

    const unsigned short* aBase = A  + (size_t)m0 * 1024;
    const unsigned short* bBase = Bt + (size_t)n0 * 1024;

    f32x4 acc[4][2];
    #pragma unroll
    for (int i = 0; i < 4; ++i)
        #pragma unroll
        for (int j = 0; j < 2; ++j)
            acc[i][j] = (f32x4){0.f, 0.f, 0.f, 0.f};

    for (int kt = 0; kt < 32; ++kt) {
        const int k0 = kt * 32;
        #pragma unroll
        for (int it = 0; it < 2; ++it) {
            const int u  = tid + it * 256;
            gload_lds16(aBase + (size_t)(u >> 2) * 1024 + k0 + (u & 3) * 8, &As[u * 8]);
        }
        gload_lds16(bBase + (size_t)(tid >> 2) * 1024 + k0 + (tid & 3) * 8, &Bs[tid * 8]);
        __syncthreads();

        bf16x8 af[4], bfr[2];
        #pragma unroll
        for (int i = 0; i < 4; ++i)
            af[i] = *(const bf16x8*)&As[(wm * 64 + i * 16 + lc) * 32 + g * 8];
        #pragma unroll
        for (int j = 0; j < 2; ++j)
            bfr[j] = *(const bf16x8*)&Bs[(wn * 32 + j * 16 + lc) * 32 + g * 8];

        #pragma unroll
        for (int i = 0; i < 4; ++i)
            #pragma unroll
            for (int j = 0; j < 2; ++j)
                acc[i][j] = __builtin_amdgcn_mfma_f32_16x16x32_bf16(af[i], bfr[j], acc[i][j], 0, 0, 0);
        __syncthreads();
    }

    #pragma unroll
    for (int i = 0; i < 4; ++i) {
        const int mrow = m0 + wm * 64 + i * 16 + g * 4;
        #pragma unroll
        for (int j = 0; j < 2; ++j) {
            const int nc = n0 + wn * 32 + j * 16 + lc;
            #pragma unroll
            for (int r = 0; r < 4; ++r)
                cf[(size_t)(mrow + r) * 1024 + nc] = acc[i][j][r];
        }
    }
}

// ---------------------------------------------------------------------------
// Flash attention v3: 32x32x16 MFMA, S^T = K Q^T, O^T = V^T P^T.
// One 256-thr block per (b,h, q-tile 64). Wave (wj = w>>1, wq2 = w&1) owns
// q-half wq2 (32 rows), j-half wj (32 of each 64-tile).
// Fixed-shift softmax (|q|=|k|=1 after rmsnorm+scale => s in [-1,1]):
// p = exp(s), lane-local scalar lsum. P^T C-layout -> PV B-frags via
// half-wave shfl_xor(32). K/V^T staged async into XOR-swizzled LDS, dbuf.
// ---------------------------------------------------------------------------
__global__ __launch_bounds__(256) void flash_attn(const unsigned short* __restrict__ qb,
                                                  const unsigned short* __restrict__ kb,
                                                  const unsigned short* __restrict__ vt,
                                                  unsigned short* __restrict__ o)
{
    __shared__ __align__(16) unsigned short smem[2 * 64 * 128 + 2 * 128 * 64 + 128];
    unsigned short* KsB = smem;
    unsigned short* VsB = smem + 2 * 64 * 128;
    float* lscr = (float*)(smem + 2 * 64 * 128 + 2 * 128 * 64);
    float* scr  = (float*)smem;                    // epilogue scratch [64][129] f32

    const int tid  = threadIdx.x;
    const int lane = tid & 63;
    const int w    = tid >> 6;
    const int wj   = w >> 1;            // j-half
    const int wq2  = w & 1;             // q-half
    const int qcol = lane & 31;
    const int hi   = lane >> 5;         // half-wave

    const int bh = blockIdx.x;
    const int h  = bh & (H_ - 1);
    const int b  = bh >> 3;
    const int yy = blockIdx.y;
    const int qt = (yy & 1) ? (31 - (yy >> 1)) : (yy >> 1);
    const int q0 = qt * 64;

    const size_t bhbase  = (size_t)b * T_ * HD + (size_t)h * 128;   // q,k,o
    const size_t bhvbase = (size_t)bh * 128 * T_;                   // vt

    int mI[4];
    size_t srcKoff[4], srcVoff[4];
    #pragma unroll
    for (int it = 0; it < 4; ++it) {
        const int m = (w * 4 + it) * 64 + lane;
        mI[it] = m;
        const int jK = m >> 4, cK = (m & 15) ^ (jK & 15);
        srcKoff[it] = (size_t)jK * 1024 + cK * 8;
        const int dV = m >> 3, cV = (m & 7) ^ (dV & 7);
        srcVoff[it] = (size_t)dV * T_ + cV * 8;
    }
    const unsigned short* kgb = kb + bhbase;
    const unsigned short* vgb = vt + bhvbase;

    // Q as B-operand frags
    bf16x8 qf[8];
    {
        const unsigned short* qp = qb + bhbase + (size_t)(q0 + wq2 * 32 + qcol) * 1024 + hi * 8;
        #pragma unroll
        for (int ks = 0; ks < 8; ++ks)
            qf[ks] = *(const bf16x8*)(qp + ks * 16);
    }

    float lsum = 0.f;
    f32x16 otacc[4];
    #pragma unroll
    for (int dch = 0; dch < 4; ++dch)
        #pragma unroll
        for (int r = 0; r < 16; ++r) otacc[dch][r] = 0.f;

    #pragma unroll
    for (int it = 0; it < 4; ++it) {
        gload_lds16(kgb + srcKoff[it], &KsB[mI[it] * 8]);
        gload_lds16(vgb + srcVoff[it], &VsB[mI[it] * 8]);
    }

    for (int jt = 0; jt <= qt; ++jt) {
        const int cur = jt & 1;
        unsigned short* Ks = KsB + cur * (64 * 128);
        unsigned short* Vs = VsB + cur * (128 * 64);
        __syncthreads();

        if (jt < qt) {
            const size_t j0n = (size_t)(jt + 1) * 64;
            unsigned short* Kn = KsB + (cur ^ 1) * (64 * 128);
            unsigned short* Vn = VsB + (cur ^ 1) * (128 * 64);
            #pragma unroll
            for (int it = 0; it < 4; ++it) {
                gload_lds16(kgb + j0n * 1024 + srcKoff[it], &Kn[mI[it] * 8]);
                gload_lds16(vgb + j0n + srcVoff[it], &Vn[mI[it] * 8]);
            }
        }

        const bool dead = (jt == qt) && (wj > wq2);
        if (!dead) {
            f32x16 sacc;
            #pragma unroll
            for (int r = 0; r < 16; ++r) sacc[r] = 0.f;
            const int jrow = wj * 32 + qcol;
            #pragma unroll
            for (int ks = 0; ks < 8; ++ks) {
                const int c = ks * 2 + hi;
                bf16x8 af = *(const bf16x8*)&Ks[(jrow * 16 + (c ^ (lane & 15))) * 8];
                sacc = __builtin_amdgcn_mfma_f32_32x32x16_bf16(af, qf[ks], sacc, 0, 0, 0);
            }

            if (jt == qt && wj == wq2) {
                #pragma unroll
                for (int r = 0; r < 16; ++r) {
                    const int jl = (r & 3) + 8 * (r >> 2) + 4 * hi;
                    if (qcol < jl) sacc[r] = -1e30f;
                }
            }

            unsigned int dw[8];
            #pragma unroll
            for (int m2 = 0; m2 < 8; ++m2) {
                const float p0 = __expf(sacc[2 * m2]);
                const float p1 = __expf(sacc[2 * m2 + 1]);
                lsum += p0 + p1;
                dw[m2] = pk2bf(p0, p1);
            }
            unsigned int ex[8];
            #pragma unroll
            for (int m2 = 0; m2 < 8; ++m2)
                ex[m2] = (unsigned int)__shfl_xor((int)dw[m2], 32);

            #pragma unroll
            for (int ks2 = 0; ks2 < 2; ++ks2) {
                union { unsigned int u[4]; bf16x8 v; } pf;
                pf.u[0] = hi ? ex[4 * ks2 + 2] : dw[4 * ks2 + 0];
                pf.u[1] = hi ? ex[4 * ks2 + 3] : dw[4 * ks2 + 1];
                pf.u[2] = hi ? dw[4 * ks2 + 2] : ex[4 * ks2 + 0];
                pf.u[3] = hi ? dw[4 * ks2 + 3] : ex[4 * ks2 + 1];
                #pragma unroll
                for (int dch = 0; dch < 4; ++dch) {
                    const int c = wj * 4 + ks2 * 2 + hi;
                    const int drow = dch * 32 + qcol;
                    bf16x8 af = *(const bf16x8*)&Vs[(drow * 8 + (c ^ (lane & 7))) * 8];
                    otacc[dch] = __builtin_amdgcn_mfma_f32_32x32x16_bf16(af, pf.v, otacc[dch], 0, 0, 0);
                }
            }
        }
    }

    // epilogue: merge wj pairs via LDS, write O bf16
    lsum += __shfl_xor(lsum, 32);
    __syncthreads();

    if (wj == 1) {
        float* s0 = scr + (size_t)(wq2 * 32 + qcol) * 129;
        #pragma unroll
        for (int dch = 0; dch < 4; ++dch)
            #pragma unroll
            for (int r = 0; r < 16; ++r)
                s0[dch * 32 + (r & 3) + 8 * (r >> 2) + 4 * hi] = otacc[dch][r];
        if (hi == 0) lscr[wq2 * 32 + qcol] = lsum;
    }
    __syncthreads();
    if (wj == 0) {
        const float l = lsum + lscr[wq2 * 32 + qcol];
        const float inv = 1.0f / l;
        const float* s0 = scr + (size_t)(wq2 * 32 + qcol) * 129;
        unsigned short* op = o + bhbase + (size_t)(q0 + wq2 * 32 + qcol) * 1024;
        #pragma unroll
        for (int dch = 0; dch < 4; ++dch) {
            #pragma unroll
            for (int k4 = 0; k4 < 4; ++k4) {
                const int d0 = dch * 32 + 8 * k4 + 4 * hi;
                const float f0 = (otacc[dch][4 * k4 + 0] + s0[d0 + 0]) * inv;
                const float f1 = (otacc[dch][4 * k4 + 1] + s0[d0 + 1]) * inv;
                const float f2 = (otacc[dch][4 * k4 + 2] + s0[d0 + 2]) * inv;
                const float f3 = (otacc[dch][4 * k4 + 3] + s0[d0 + 3]) * inv;
                uint2 val;
                val.x = pk2bf(f0, f1);
                val.y = pk2bf(f2, f3);
                *(uint2*)(op + d0) = val;
            }
        }
    }
}

// ---------------------------------------------------------------------------
extern "C" void kernel_launch(void* const* d_in, const int* in_sizes, int n_in,
                              void* d_out, int out_size, void* d_ws, size_t ws_size,
                              hipStream_t stream)
{
    const float* x  = (const float*)d_in[0];
    const float* wq = (const float*)d_in[1];
    const float* wk = (const float*)d_in[2];
    const float* wv = (const float*)d_in[3];
    const float* wo = (const float*)d_in[4];
    float* out = (float*)d_out;

    const size_t SZ = (size_t)NROW * HD;               // 4M elements
    unsigned short* qb    = (unsigned short*)d_ws;     // 8 MB
    unsigned short* kb    = qb + SZ;                   // 8 MB
    unsigned short* vt    = kb + SZ;                   // 8 MB [(b,h),d,t]
    unsigned short* ob    = vt + SZ;                   // 8 MB
    unsigned short* xb    = ob + SZ;                   // 8 MB
    unsigned short* wqkvT = xb + SZ;                   // 6 MB [3072][1024]
    unsigned short* woT   = wqkvT + 3 * 1024 * 1024;   // 2 MB

    // prologue: x cast + 4 weight transposes, one launch
    prep<<<dim3(32, 32, 5), 256, 0, stream>>>(x, wq, wk, wv, wo, xb, wqkvT, woT);

    // fused QKV projection (+ RMSNorm/RoPE on q,k; V written transposed)
    gemm_qkv<<<dim3(24, 32), 256, 0, stream>>>(xb, wqkvT, qb, kb, vt);

    flash_attn<<<dim3(B_ * H_, 32), 256, 0, stream>>>(qb, kb, vt, ob);

    // output projection, 128x64 tiles -> 512 blocks
    gemm_out<<<dim3(16, 32), 256, 0, stream>>>(ob, woT, out);
}

// Round 8
// 188.995 us; speedup vs baseline: 1.1354x; 1.0379x over previous
//
#include <hip/hip_runtime.h>
#include <hip/hip_bf16.h>
#include <math.h>

// Problem constants: B=2, T=2048, M=1024, H=8, D=128
#define B_  2
#define T_  2048
#define M_  1024
#define H_  8
#define D_  128
#define NROW (B_ * T_)          // 4096
#define HD  (H_ * D_)           // 1024

#define NORM_EPS 1e-6f
#define QK_MULT  0.08838834764831845f   // sqrt(1/128)
#define LN_BASE_64 0.14391156510f       // ln(10000)/64

typedef short bf16x8  __attribute__((ext_vector_type(8)));    // 8 bf16 = 4 VGPRs
typedef float f32x4   __attribute__((ext_vector_type(4)));
typedef float f32x16  __attribute__((ext_vector_type(16)));

static __device__ __forceinline__ unsigned short f2bf(float f) {
    union { __hip_bfloat16 h; unsigned short u; } cv;
    cv.h = __float2bfloat16(f);
    return cv.u;
}
static __device__ __forceinline__ float bf2f(unsigned short u) {
    union { unsigned short u; __hip_bfloat16 h; } cv;
    cv.u = u;
    return __bfloat162float(cv.h);
}
static __device__ __forceinline__ unsigned int pk2bf(float a, float b) {
    return ((unsigned int)f2bf(b) << 16) | f2bf(a);
}

// async global->LDS, 16 bytes per lane. LDS dest = wave-uniform base + lane*16.
static __device__ __forceinline__ void gload_lds16(const unsigned short* g,
                                                   unsigned short* l) {
    __builtin_amdgcn_global_load_lds(
        (const __attribute__((address_space(1))) void*)g,
        (__attribute__((address_space(3))) void*)l, 16, 0, 0);
}

// ---------------------------------------------------------------------------
// prep: z<4 -> transpose+cast weight z (out[n][k]=bf16(in[k][n]));
//       z==4 -> linear cast of x to bf16.
// ---------------------------------------------------------------------------
__global__ __launch_bounds__(256) void prep(const float* __restrict__ x,
                                            const float* __restrict__ w0,
                                            const float* __restrict__ w1,
                                            const float* __restrict__ w2,
                                            const float* __restrict__ w3,
                                            unsigned short* __restrict__ xb,
                                            unsigned short* __restrict__ wqkvT,
                                            unsigned short* __restrict__ woT)
{
    __shared__ float t[32][33];
    const int z = blockIdx.z;
    if (z == 4) {
        const size_t base = ((size_t)blockIdx.y * 32 + blockIdx.x) * 4096;
        #pragma unroll
        for (int it = 0; it < 4; ++it) {
            const size_t i = base + it * 1024 + threadIdx.x * 4;
            const float4 v = *(const float4*)(x + i);
            ushort4 o;
            o.x = f2bf(v.x); o.y = f2bf(v.y); o.z = f2bf(v.z); o.w = f2bf(v.w);
            *(ushort4*)(xb + i) = o;
        }
        return;
    }
    const float* in = z == 0 ? w0 : (z == 1 ? w1 : (z == 2 ? w2 : w3));
    unsigned short* out = z < 3 ? (wqkvT + (size_t)z * 1024 * 1024) : woT;

    const int tx = threadIdx.x & 31;
    const int ty = threadIdx.x >> 5;
    const int n0 = blockIdx.x * 32;
    const int k0 = blockIdx.y * 32;
    #pragma unroll
    for (int r = 0; r < 4; ++r)
        t[ty + r * 8][tx] = in[(size_t)(k0 + ty + r * 8) * 1024 + n0 + tx];
    __syncthreads();
    #pragma unroll
    for (int r = 0; r < 4; ++r)
        out[(size_t)(n0 + ty + r * 8) * 1024 + k0 + tx] = f2bf(t[tx][ty + r * 8]);
}

// ---------------------------------------------------------------------------
// QKV GEMM: C = A[4096x1024] * Bt[3072x1024]^T.  128x128 tile, BK=64
// (16 k-iterations -> half the barrier drains of BK=32). LDS rows are
// XOR-chunk-swizzled (seg ^ (row&7)) so BK=64 fragment reads stay 2-way
// (free); staging is a permuted in-row fetch (DMA-compatible).
// 4x1 wave layout: wave owns 32 rows x all 128 cols, so the RoPE pair
// (d, d+64) = (acc j, acc j+4) is register-local (no LDS exchange).
// q,k: fused RMSNorm+RoPE, written [b,t,h,d]. V: transposed to vt[(b,h),d,t].
// ---------------------------------------------------------------------------
__global__ __launch_bounds__(256) void gemm_qkv(const unsigned short* __restrict__ A,
                                                const unsigned short* __restrict__ Bt,
                                                unsigned short* __restrict__ oq,
                                                unsigned short* __restrict__ ok,
                                                unsigned short* __restrict__ vt)
{
    __shared__ unsigned short As[128 * 64];   // 16 KB
    __shared__ unsigned short Bs[128 * 64];   // 16 KB

    const int tid  = threadIdx.x;
    const int lane = tid & 63;
    const int w    = tid >> 6;          // wave = row band (32 rows)
    const int g    = lane >> 4;
    const int lc   = lane & 15;

    const int m0 = blockIdx.y * 128;
    const int n0 = blockIdx.x * 128;

    const unsigned short* aBase = A  + (size_t)m0 * 1024;
    const unsigned short* bBase = Bt + (size_t)n0 * 1024;

    f32x4 acc[2][8];
    #pragma unroll
    for (int i = 0; i < 2; ++i)
        #pragma unroll
        for (int j = 0; j < 8; ++j)
            acc[i][j] = (f32x4){0.f, 0.f, 0.f, 0.f};

    for (int kt = 0; kt < 16; ++kt) {
        const int k0 = kt * 64;
        #pragma unroll
        for (int it = 0; it < 4; ++it) {
            const int u  = tid + it * 256;      // 0..1023
            const int r2 = u >> 3;              // tile row
            const int s2 = u & 7;               // dest 16B segment
            const int sg = s2 ^ (r2 & 7);       // src segment (XOR swizzle)
            gload_lds16(aBase + (size_t)r2 * 1024 + k0 + sg * 8, &As[u * 8]);
            gload_lds16(bBase + (size_t)r2 * 1024 + k0 + sg * 8, &Bs[u * 8]);
        }
        __syncthreads();

        #pragma unroll
        for (int dc = 0; dc < 2; ++dc) {
            const int sw = ((dc * 4 + g) ^ (lc & 7)) << 3;
            bf16x8 af[2], bfr[8];
            #pragma unroll
            for (int i = 0; i < 2; ++i)
                af[i] = *(const bf16x8*)&As[(w * 32 + i * 16 + lc) * 64 + sw];
            #pragma unroll
            for (int j = 0; j < 8; ++j)
                bfr[j] = *(const bf16x8*)&Bs[(j * 16 + lc) * 64 + sw];

            #pragma unroll
            for (int i = 0; i < 2; ++i)
                #pragma unroll
                for (int j = 0; j < 8; ++j)
                    acc[i][j] = __builtin_amdgcn_mfma_f32_16x16x32_bf16(af[i], bfr[j], acc[i][j], 0, 0, 0);
        }
        __syncthreads();
    }

    const int which = n0 >> 10;
    const int ncol0 = n0 & 1023;            // head-aligned (tile = one head)
    if (which < 2) {
        // ---- fused RMSNorm + RoPE + sqrt(qk_scale) for q / k ----
        unsigned short* outp = which == 0 ? oq : ok;
        float freq[4];
        #pragma unroll
        for (int j = 0; j < 4; ++j)
            freq[j] = __expf(-(float)(j * 16 + lc) * LN_BASE_64);

        #pragma unroll
        for (int i = 0; i < 2; ++i)
            #pragma unroll
            for (int r = 0; r < 4; ++r) {
                float s = 0.f;
                #pragma unroll
                for (int j = 0; j < 8; ++j) s += acc[i][j][r] * acc[i][j][r];
                #pragma unroll
                for (int off = 1; off < 16; off <<= 1) s += __shfl_xor(s, off);
                const float rms = rsqrtf(s * (1.0f / 128.0f) + NORM_EPS) * QK_MULT;

                const int trow = m0 + w * 32 + i * 16 + g * 4 + r;
                const float tpos = (float)(trow & (T_ - 1));
                unsigned short* op = outp + (size_t)trow * 1024 + ncol0;
                #pragma unroll
                for (int j = 0; j < 4; ++j) {
                    float sn, cs;
                    __sincosf(tpos * freq[j], &sn, &cs);
                    const float e = acc[i][j][r] * rms;       // even half
                    const float o = acc[i][j + 4][r] * rms;   // odd half (+64)
                    op[j * 16 + lc]      = f2bf(e * cs - o * sn);
                    op[j * 16 + lc + 64] = f2bf(e * sn + o * cs);
                }
            }
    } else {
        // V: write transposed -> vt[(b*8+h)*128 + d][t], packed 4x bf16
        const int b2 = m0 >> 11;
        const int hh = ncol0 >> 7;
        #pragma unroll
        for (int i = 0; i < 2; ++i) {
            const int t = (m0 & 2047) + w * 32 + i * 16 + g * 4;  // +r
            #pragma unroll
            for (int j = 0; j < 8; ++j) {
                const int dd = j * 16 + lc;
                uint2 val;
                val.x = pk2bf(acc[i][j][0], acc[i][j][1]);
                val.y = pk2bf(acc[i][j][2], acc[i][j][3]);
                *(uint2*)(vt + (((size_t)(b2 * 8 + hh) * 128 + dd) * T_ + t)) = val;
            }
        }
    }
}

// ---------------------------------------------------------------------------
// Output projection: C[4096x1024] fp32 = A * Bt^T. 128x64 tile (512 blocks,
// 2/CU), BK=64 with XOR-swizzled LDS (same scheme as gemm_qkv).
// 2x2 waves of 64x32.
// ---------------------------------------------------------------------------
__global__ __launch_bounds__(256) void gemm_out(const unsigned short* __restrict__ A,
                                                const unsigned short* __restrict__ Bt,
                                                float* __restrict__ cf)
{
    __shared__ unsigned short As[128 * 64];   // 16 KB
    __shared__ unsigned short Bs[64 * 64];    // 8 KB

    const int tid  = threadIdx.x;
    const int lane = tid & 63;
    const int w    = tid >> 6;
    const int g    = lane >> 4;
    const int lc   = lane & 15;
    const int wm   = w >> 1;
    const int wn   = w & 1;

    const int m0 = blockIdx.y * 128;
    const int n0 = blockIdx.x * 64;

    const unsigned short* aBase = A  + (size_t)m0 * 1024;
    const unsigned short* bBase = Bt + (size_t)n0 * 1024;

    f32x4 acc[4][2];
    #pragma unroll
    for (int i = 0; i < 4; ++i)
        #pragma unroll
        for (int j = 0; j < 2; ++j)
            acc[i][j] = (f32x4){0.f, 0.f, 0.f, 0.f};

    for (int kt = 0; kt < 16; ++kt) {
        const int k0 = kt * 64;
        #pragma unroll
        for (int it = 0; it < 4; ++it) {
            const int u  = tid + it * 256;      // 0..1023
            const int r2 = u >> 3;
            const int sg = (u & 7) ^ (r2 & 7);
            gload_lds16(aBase + (size_t)r2 * 1024 + k0 + sg * 8, &As[u * 8]);
        }
        #pragma unroll
        for (int it = 0; it < 2; ++it) {
            const int u  = tid + it * 256;      // 0..511
            const int r2 = u >> 3;
            const int sg = (u & 7) ^ (r2 & 7);
            gload_lds16(bBase + (size_t)r2 * 1024 + k0 + sg * 8, &Bs[u * 8]);
        }
        __syncthreads();

        #pragma unroll
        for (int dc = 0; dc < 2; ++dc) {
            const int sw = ((dc * 4 + g) ^ (lc & 7)) << 3;
            bf16x8 af[4], bfr[2];
            #pragma unroll
            for (int i = 0; i < 4; ++i)
                af[i] = *(const bf16x8*)&As[(wm * 64 + i * 16 + lc) * 64 + sw];
            #pragma unroll
            for (int j = 0; j < 2; ++j)
                bfr[j] = *(const bf16x8*)&Bs[(wn * 32 + j * 16 + lc) * 64 + sw];

            #pragma unroll
            for (int i = 0; i < 4; ++i)
                #pragma unroll
                for (int j = 0; j < 2; ++j)
                    acc[i][j] = __builtin_amdgcn_mfma_f32_16x16x32_bf16(af[i], bfr[j], acc[i][j], 0, 0, 0);
        }
        __syncthreads();
    }

    #pragma unroll
    for (int i = 0; i < 4; ++i) {
        const int mrow = m0 + wm * 64 + i * 16 + g * 4;
        #pragma unroll
        for (int j = 0; j < 2; ++j) {
            const int nc = n0 + wn * 32 + j * 16 + lc;
            #pragma unroll
            for (int r = 0; r < 4; ++r)
                cf[(size_t)(mrow + r) * 1024 + nc] = acc[i][j][r];
        }
    }
}

// ---------------------------------------------------------------------------
// Flash attention v3: 32x32x16 MFMA, S^T = K Q^T, O^T = V^T P^T.
// One 256-thr block per (b,h, q-tile 64). Wave (wj = w>>1, wq2 = w&1) owns
// q-half wq2 (32 rows), j-half wj (32 of each 64-tile).
// Fixed-shift softmax (|q|=|k|=1 after rmsnorm+scale => s in [-1,1]):
// p = exp(s), lane-local scalar lsum. P^T C-layout -> PV B-frags via
// half-wave shfl_xor(32). K/V^T staged async into XOR-swizzled LDS, dbuf.
// ---------------------------------------------------------------------------
__global__ __launch_bounds__(256) void flash_attn(const unsigned short* __restrict__ qb,
                                                  const unsigned short* __restrict__ kb,
                                                  const unsigned short* __restrict__ vt,
                                                  unsigned short* __restrict__ o)
{
    __shared__ __align__(16) unsigned short smem[2 * 64 * 128 + 2 * 128 * 64 + 128];
    unsigned short* KsB = smem;
    unsigned short* VsB = smem + 2 * 64 * 128;
    float* lscr = (float*)(smem + 2 * 64 * 128 + 2 * 128 * 64);
    float* scr  = (float*)smem;                    // epilogue scratch [64][129] f32

    const int tid  = threadIdx.x;
    const int lane = tid & 63;
    const int w    = tid >> 6;
    const int wj   = w >> 1;            // j-half
    const int wq2  = w & 1;             // q-half
    const int qcol = lane & 31;
    const int hi   = lane >> 5;         // half-wave

    const int bh = blockIdx.x;
    const int h  = bh & (H_ - 1);
    const int b  = bh >> 3;
    const int yy = blockIdx.y;
    const int qt = (yy & 1) ? (31 - (yy >> 1)) : (yy >> 1);
    const int q0 = qt * 64;

    const size_t bhbase  = (size_t)b * T_ * HD + (size_t)h * 128;   // q,k,o
    const size_t bhvbase = (size_t)bh * 128 * T_;                   // vt

    int mI[4];
    size_t srcKoff[4], srcVoff[4];
    #pragma unroll
    for (int it = 0; it < 4; ++it) {
        const int m = (w * 4 + it) * 64 + lane;
        mI[it] = m;
        const int jK = m >> 4, cK = (m & 15) ^ (jK & 15);
        srcKoff[it] = (size_t)jK * 1024 + cK * 8;
        const int dV = m >> 3, cV = (m & 7) ^ (dV & 7);
        srcVoff[it] = (size_t)dV * T_ + cV * 8;
    }
    const unsigned short* kgb = kb + bhbase;
    const unsigned short* vgb = vt + bhvbase;

    // Q as B-operand frags
    bf16x8 qf[8];
    {
        const unsigned short* qp = qb + bhbase + (size_t)(q0 + wq2 * 32 + qcol) * 1024 + hi * 8;
        #pragma unroll
        for (int ks = 0; ks < 8; ++ks)
            qf[ks] = *(const bf16x8*)(qp + ks * 16);
    }

    float lsum = 0.f;
    f32x16 otacc[4];
    #pragma unroll
    for (int dch = 0; dch < 4; ++dch)
        #pragma unroll
        for (int r = 0; r < 16; ++r) otacc[dch][r] = 0.f;

    #pragma unroll
    for (int it = 0; it < 4; ++it) {
        gload_lds16(kgb + srcKoff[it], &KsB[mI[it] * 8]);
        gload_lds16(vgb + srcVoff[it], &VsB[mI[it] * 8]);
    }

    for (int jt = 0; jt <= qt; ++jt) {
        const int cur = jt & 1;
        unsigned short* Ks = KsB + cur * (64 * 128);
        unsigned short* Vs = VsB + cur * (128 * 64);
        __syncthreads();

        if (jt < qt) {
            const size_t j0n = (size_t)(jt + 1) * 64;
            unsigned short* Kn = KsB + (cur ^ 1) * (64 * 128);
            unsigned short* Vn = VsB + (cur ^ 1) * (128 * 64);
            #pragma unroll
            for (int it = 0; it < 4; ++it) {
                gload_lds16(kgb + j0n * 1024 + srcKoff[it], &Kn[mI[it] * 8]);
                gload_lds16(vgb + j0n + srcVoff[it], &Vn[mI[it] * 8]);
            }
        }

        const bool dead = (jt == qt) && (wj > wq2);
        if (!dead) {
            f32x16 sacc;
            #pragma unroll
            for (int r = 0; r < 16; ++r) sacc[r] = 0.f;
            const int jrow = wj * 32 + qcol;
            #pragma unroll
            for (int ks = 0; ks < 8; ++ks) {
                const int c = ks * 2 + hi;
                bf16x8 af = *(const bf16x8*)&Ks[(jrow * 16 + (c ^ (lane & 15))) * 8];
                sacc = __builtin_amdgcn_mfma_f32_32x32x16_bf16(af, qf[ks], sacc, 0, 0, 0);
            }

            if (jt == qt && wj == wq2) {
                #pragma unroll
                for (int r = 0; r < 16; ++r) {
                    const int jl = (r & 3) + 8 * (r >> 2) + 4 * hi;
                    if (qcol < jl) sacc[r] = -1e30f;
                }
            }

            unsigned int dw[8];
            #pragma unroll
            for (int m2 = 0; m2 < 8; ++m2) {
                const float p0 = __expf(sacc[2 * m2]);
                const float p1 = __expf(sacc[2 * m2 + 1]);
                lsum += p0 + p1;
                dw[m2] = pk2bf(p0, p1);
            }
            unsigned int ex[8];
            #pragma unroll
            for (int m2 = 0; m2 < 8; ++m2)
                ex[m2] = (unsigned int)__shfl_xor((int)dw[m2], 32);

            #pragma unroll
            for (int ks2 = 0; ks2 < 2; ++ks2) {
                union { unsigned int u[4]; bf16x8 v; } pf;
                pf.u[0] = hi ? ex[4 * ks2 + 2] : dw[4 * ks2 + 0];
                pf.u[1] = hi ? ex[4 * ks2 + 3] : dw[4 * ks2 + 1];
                pf.u[2] = hi ? dw[4 * ks2 + 2] : ex[4 * ks2 + 0];
                pf.u[3] = hi ? dw[4 * ks2 + 3] : ex[4 * ks2 + 1];
                #pragma unroll
                for (int dch = 0; dch < 4; ++dch) {
                    const int c = wj * 4 + ks2 * 2 + hi;
                    const int drow = dch * 32 + qcol;
                    bf16x8 af = *(const bf16x8*)&Vs[(drow * 8 + (c ^ (lane & 7))) * 8];
                    otacc[dch] = __builtin_amdgcn_mfma_f32_32x32x16_bf16(af, pf.v, otacc[dch], 0, 0, 0);
                }
            }
        }
    }

    // epilogue: merge wj pairs via LDS, write O bf16
    lsum += __shfl_xor(lsum, 32);
    __syncthreads();

    if (wj == 1) {
        float* s0 = scr + (size_t)(wq2 * 32 + qcol) * 129;
        #pragma unroll
        for (int dch = 0; dch < 4; ++dch)
            #pragma unroll
            for (int r = 0; r < 16; ++r)
                s0[dch * 32 + (r & 3) + 8 * (r >> 2) + 4 * hi] = otacc[dch][r];
        if (hi == 0) lscr[wq2 * 32 + qcol] = lsum;
    }
    __syncthreads();
    if (wj == 0) {
        const float l = lsum + lscr[wq2 * 32 + qcol];
        const float inv = 1.0f / l;
        const float* s0 = scr + (size_t)(wq2 * 32 + qcol) * 129;
        unsigned short* op = o + bhbase + (size_t)(q0 + wq2 * 32 + qcol) * 1024;
        #pragma unroll
        for (int dch = 0; dch < 4; ++dch) {
            #pragma unroll
            for (int k4 = 0; k4 < 4; ++k4) {
                const int d0 = dch * 32 + 8 * k4 + 4 * hi;
                const float f0 = (otacc[dch][4 * k4 + 0] + s0[d0 + 0]) * inv;
                const float f1 = (otacc[dch][4 * k4 + 1] + s0[d0 + 1]) * inv;
                const float f2 = (otacc[dch][4 * k4 + 2] + s0[d0 + 2]) * inv;
                const float f3 = (otacc[dch][4 * k4 + 3] + s0[d0 + 3]) * inv;
                uint2 val;
                val.x = pk2bf(f0, f1);
                val.y = pk2bf(f2, f3);
                *(uint2*)(op + d0) = val;
            }
        }
    }
}

// ---------------------------------------------------------------------------
extern "C" void kernel_launch(void* const* d_in, const int* in_sizes, int n_in,
                              void* d_out, int out_size, void* d_ws, size_t ws_size,
                              hipStream_t stream)
{
    const float* x  = (const float*)d_in[0];
    const float* wq = (const float*)d_in[1];
    const float* wk = (const float*)d_in[2];
    const float* wv = (const float*)d_in[3];
    const float* wo = (const float*)d_in[4];
    float* out = (float*)d_out;

    const size_t SZ = (size_t)NROW * HD;               // 4M elements
    unsigned short* qb    = (unsigned short*)d_ws;     // 8 MB
    unsigned short* kb    = qb + SZ;                   // 8 MB
    unsigned short* vt    = kb + SZ;                   // 8 MB [(b,h),d,t]
    unsigned short* ob    = vt + SZ;                   // 8 MB
    unsigned short* xb    = ob + SZ;                   // 8 MB
    unsigned short* wqkvT = xb + SZ;                   // 6 MB [3072][1024]
    unsigned short* woT   = wqkvT + 3 * 1024 * 1024;   // 2 MB

    // prologue: x cast + 4 weight transposes, one launch
    prep<<<dim3(32, 32, 5), 256, 0, stream>>>(x, wq, wk, wv, wo, xb, wqkvT, woT);

    // fused QKV projection (+ RMSNorm/RoPE on q,k; V written transposed)
    gemm_qkv<<<dim3(24, 32), 256, 0, stream>>>(xb, wqkvT, qb, kb, vt);

    flash_attn<<<dim3(B_ * H_, 32), 256, 0, stream>>>(qb, kb, vt, ob);

    // output projection, 128x64 tiles -> 512 blocks
    gemm_out<<<dim3(16, 32), 256, 0, stream>>>(ob, woT, out);
}

// Round 9
// 186.612 us; speedup vs baseline: 1.1499x; 1.0128x over previous
//
#include <hip/hip_runtime.h>
#include <hip/hip_bf16.h>
#include <math.h>

// Problem constants: B=2, T=2048, M=1024, H=8, D=128
#define B_  2
#define T_  2048
#define M_  1024
#define H_  8
#define D_  128
#define NROW (B_ * T_)          // 4096
#define HD  (H_ * D_)           // 1024

#define NORM_EPS 1e-6f
#define QK_MULT  0.08838834764831845f   // sqrt(1/128)
#define LN_BASE_64 0.14391156510f       // ln(10000)/64

typedef short bf16x8  __attribute__((ext_vector_type(8)));    // 8 bf16 = 4 VGPRs
typedef float f32x4   __attribute__((ext_vector_type(4)));
typedef float f32x16  __attribute__((ext_vector_type(16)));

static __device__ __forceinline__ unsigned short f2bf(float f) {
    union { __hip_bfloat16 h; unsigned short u; } cv;
    cv.h = __float2bfloat16(f);
    return cv.u;
}
static __device__ __forceinline__ float bf2f(unsigned short u) {
    union { unsigned short u; __hip_bfloat16 h; } cv;
    cv.u = u;
    return __bfloat162float(cv.h);
}
static __device__ __forceinline__ unsigned int pk2bf(float a, float b) {
    return ((unsigned int)f2bf(b) << 16) | f2bf(a);
}

// async global->LDS, 16 bytes per lane. LDS dest = wave-uniform base + lane*16.
static __device__ __forceinline__ void gload_lds16(const unsigned short* g,
                                                   unsigned short* l) {
    __builtin_amdgcn_global_load_lds(
        (const __attribute__((address_space(1))) void*)g,
        (__attribute__((address_space(3))) void*)l, 16, 0, 0);
}

// ---------------------------------------------------------------------------
// prep: z<4 -> transpose+cast weight z (out[n][k]=bf16(in[k][n]));
//       z==4 -> linear cast of x to bf16.
// ---------------------------------------------------------------------------
__global__ __launch_bounds__(256) void prep(const float* __restrict__ x,
                                            const float* __restrict__ w0,
                                            const float* __restrict__ w1,
                                            const float* __restrict__ w2,
                                            const float* __restrict__ w3,
                                            unsigned short* __restrict__ xb,
                                            unsigned short* __restrict__ wqkvT,
                                            unsigned short* __restrict__ woT)
{
    __shared__ float t[32][33];
    const int z = blockIdx.z;
    if (z == 4) {
        const size_t base = ((size_t)blockIdx.y * 32 + blockIdx.x) * 4096;
        #pragma unroll
        for (int it = 0; it < 4; ++it) {
            const size_t i = base + it * 1024 + threadIdx.x * 4;
            const float4 v = *(const float4*)(x + i);
            ushort4 o;
            o.x = f2bf(v.x); o.y = f2bf(v.y); o.z = f2bf(v.z); o.w = f2bf(v.w);
            *(ushort4*)(xb + i) = o;
        }
        return;
    }
    const float* in = z == 0 ? w0 : (z == 1 ? w1 : (z == 2 ? w2 : w3));
    unsigned short* out = z < 3 ? (wqkvT + (size_t)z * 1024 * 1024) : woT;

    const int tx = threadIdx.x & 31;
    const int ty = threadIdx.x >> 5;
    const int n0 = blockIdx.x * 32;
    const int k0 = blockIdx.y * 32;
    #pragma unroll
    for (int r = 0; r < 4; ++r)
        t[ty + r * 8][tx] = in[(size_t)(k0 + ty + r * 8) * 1024 + n0 + tx];
    __syncthreads();
    #pragma unroll
    for (int r = 0; r < 4; ++r)
        out[(size_t)(n0 + ty + r * 8) * 1024 + k0 + tx] = f2bf(t[tx][ty + r * 8]);
}

// ---------------------------------------------------------------------------
// QKV GEMM: C = A[4096x1024] * Bt[3072x1024]^T. 128x128 tile, BK=64,
// ASYNC DOUBLE-BUFFERED staging (flash-proven pattern): prefetch tile kt+1
// via global_load_lds right after the barrier, during compute on tile kt ->
// one barrier per k-iter and the vmcnt drain finds the DMA landed.
// XOR-chunk-swizzled LDS (seg ^ (row&7)): conflict-free, DMA-compatible.
// 4x1 wave layout (wave = 32 rows x all 128 cols) keeps the RoPE pair
// (d, d+64) = (acc j, acc j+4) register-local.
// q,k: fused RMSNorm+RoPE, written [b,t,h,d]. V: transposed to vt[(b,h),d,t].
// ---------------------------------------------------------------------------
__global__ __launch_bounds__(256) void gemm_qkv(const unsigned short* __restrict__ A,
                                                const unsigned short* __restrict__ Bt,
                                                unsigned short* __restrict__ oq,
                                                unsigned short* __restrict__ ok,
                                                unsigned short* __restrict__ vt)
{
    __shared__ unsigned short As[2][128 * 64];   // 2 x 16 KB
    __shared__ unsigned short Bs[2][128 * 64];   // 2 x 16 KB  (64 KB total)

    const int tid  = threadIdx.x;
    const int lane = tid & 63;
    const int w    = tid >> 6;          // wave = row band (32 rows)
    const int g    = lane >> 4;
    const int lc   = lane & 15;

    const int m0 = blockIdx.y * 128;
    const int n0 = blockIdx.x * 128;

    const unsigned short* aBase = A  + (size_t)m0 * 1024;
    const unsigned short* bBase = Bt + (size_t)n0 * 1024;

    // loop-invariant staging offsets: thread stages 4 chunks of A and B
    int dstOff[4];
    size_t srcOff[4];
    #pragma unroll
    for (int it = 0; it < 4; ++it) {
        const int u  = tid + it * 256;      // 0..1023
        const int r2 = u >> 3;              // tile row
        const int sg = (u & 7) ^ (r2 & 7);  // src segment (XOR swizzle)
        dstOff[it] = u * 8;
        srcOff[it] = (size_t)r2 * 1024 + sg * 8;
    }

    f32x4 acc[2][8];
    #pragma unroll
    for (int i = 0; i < 2; ++i)
        #pragma unroll
        for (int j = 0; j < 8; ++j)
            acc[i][j] = (f32x4){0.f, 0.f, 0.f, 0.f};

    // prologue: stage tile 0 into buffer 0
    #pragma unroll
    for (int it = 0; it < 4; ++it) {
        gload_lds16(aBase + srcOff[it], &As[0][dstOff[it]]);
        gload_lds16(bBase + srcOff[it], &Bs[0][dstOff[it]]);
    }

    for (int kt = 0; kt < 16; ++kt) {
        const int cur = kt & 1;
        __syncthreads();                      // tile kt ready; buf^1 free

        if (kt < 15) {                        // async-prefetch next K-tile
            const int k0n = (kt + 1) * 64;
            #pragma unroll
            for (int it = 0; it < 4; ++it) {
                gload_lds16(aBase + srcOff[it] + k0n, &As[cur ^ 1][dstOff[it]]);
                gload_lds16(bBase + srcOff[it] + k0n, &Bs[cur ^ 1][dstOff[it]]);
            }
        }

        #pragma unroll
        for (int dc = 0; dc < 2; ++dc) {
            const int sw = ((dc * 4 + g) ^ (lc & 7)) << 3;
            bf16x8 af[2], bfr[8];
            #pragma unroll
            for (int i = 0; i < 2; ++i)
                af[i] = *(const bf16x8*)&As[cur][(w * 32 + i * 16 + lc) * 64 + sw];
            #pragma unroll
            for (int j = 0; j < 8; ++j)
                bfr[j] = *(const bf16x8*)&Bs[cur][(j * 16 + lc) * 64 + sw];

            #pragma unroll
            for (int i = 0; i < 2; ++i)
                #pragma unroll
                for (int j = 0; j < 8; ++j)
                    acc[i][j] = __builtin_amdgcn_mfma_f32_16x16x32_bf16(af[i], bfr[j], acc[i][j], 0, 0, 0);
        }
    }

    const int which = n0 >> 10;
    const int ncol0 = n0 & 1023;            // head-aligned (tile = one head)
    if (which < 2) {
        // ---- fused RMSNorm + RoPE + sqrt(qk_scale) for q / k ----
        unsigned short* outp = which == 0 ? oq : ok;
        float freq[4];
        #pragma unroll
        for (int j = 0; j < 4; ++j)
            freq[j] = __expf(-(float)(j * 16 + lc) * LN_BASE_64);

        #pragma unroll
        for (int i = 0; i < 2; ++i)
            #pragma unroll
            for (int r = 0; r < 4; ++r) {
                float s = 0.f;
                #pragma unroll
                for (int j = 0; j < 8; ++j) s += acc[i][j][r] * acc[i][j][r];
                #pragma unroll
                for (int off = 1; off < 16; off <<= 1) s += __shfl_xor(s, off);
                const float rms = rsqrtf(s * (1.0f / 128.0f) + NORM_EPS) * QK_MULT;

                const int trow = m0 + w * 32 + i * 16 + g * 4 + r;
                const float tpos = (float)(trow & (T_ - 1));
                unsigned short* op = outp + (size_t)trow * 1024 + ncol0;
                #pragma unroll
                for (int j = 0; j < 4; ++j) {
                    float sn, cs;
                    __sincosf(tpos * freq[j], &sn, &cs);
                    const float e = acc[i][j][r] * rms;       // even half
                    const float o = acc[i][j + 4][r] * rms;   // odd half (+64)
                    op[j * 16 + lc]      = f2bf(e * cs - o * sn);
                    op[j * 16 + lc + 64] = f2bf(e * sn + o * cs);
                }
            }
    } else {
        // V: write transposed -> vt[(b*8+h)*128 + d][t], packed 4x bf16
        const int b2 = m0 >> 11;
        const int hh = ncol0 >> 7;
        #pragma unroll
        for (int i = 0; i < 2; ++i) {
            const int t = (m0 & 2047) + w * 32 + i * 16 + g * 4;  // +r
            #pragma unroll
            for (int j = 0; j < 8; ++j) {
                const int dd = j * 16 + lc;
                uint2 val;
                val.x = pk2bf(acc[i][j][0], acc[i][j][1]);
                val.y = pk2bf(acc[i][j][2], acc[i][j][3]);
                *(uint2*)(vt + (((size_t)(b2 * 8 + hh) * 128 + dd) * T_ + t)) = val;
            }
        }
    }
}

// ---------------------------------------------------------------------------
// Output projection: C[4096x1024] fp32 = A * Bt^T. 128x64 tile (512 blocks,
// 2/CU), BK=64, async double-buffered staging + XOR swizzle (as gemm_qkv).
// 2x2 waves of 64x32.
// ---------------------------------------------------------------------------
__global__ __launch_bounds__(256) void gemm_out(const unsigned short* __restrict__ A,
                                                const unsigned short* __restrict__ Bt,
                                                float* __restrict__ cf)
{
    __shared__ unsigned short As[2][128 * 64];   // 2 x 16 KB
    __shared__ unsigned short Bs[2][64 * 64];    // 2 x 8 KB  (48 KB total)

    const int tid  = threadIdx.x;
    const int lane = tid & 63;
    const int w    = tid >> 6;
    const int g    = lane >> 4;
    const int lc   = lane & 15;
    const int wm   = w >> 1;
    const int wn   = w & 1;

    const int m0 = blockIdx.y * 128;
    const int n0 = blockIdx.x * 64;

    const unsigned short* aBase = A  + (size_t)m0 * 1024;
    const unsigned short* bBase = Bt + (size_t)n0 * 1024;

    int dstA[4], dstB[2];
    size_t srcA[4], srcB[2];
    #pragma unroll
    for (int it = 0; it < 4; ++it) {
        const int u  = tid + it * 256;
        const int r2 = u >> 3;
        const int sg = (u & 7) ^ (r2 & 7);
        dstA[it] = u * 8;
        srcA[it] = (size_t)r2 * 1024 + sg * 8;
    }
    #pragma unroll
    for (int it = 0; it < 2; ++it) {
        const int u  = tid + it * 256;
        const int r2 = u >> 3;
        const int sg = (u & 7) ^ (r2 & 7);
        dstB[it] = u * 8;
        srcB[it] = (size_t)r2 * 1024 + sg * 8;
    }

    f32x4 acc[4][2];
    #pragma unroll
    for (int i = 0; i < 4; ++i)
        #pragma unroll
        for (int j = 0; j < 2; ++j)
            acc[i][j] = (f32x4){0.f, 0.f, 0.f, 0.f};

    #pragma unroll
    for (int it = 0; it < 4; ++it)
        gload_lds16(aBase + srcA[it], &As[0][dstA[it]]);
    #pragma unroll
    for (int it = 0; it < 2; ++it)
        gload_lds16(bBase + srcB[it], &Bs[0][dstB[it]]);

    for (int kt = 0; kt < 16; ++kt) {
        const int cur = kt & 1;
        __syncthreads();

        if (kt < 15) {
            const int k0n = (kt + 1) * 64;
            #pragma unroll
            for (int it = 0; it < 4; ++it)
                gload_lds16(aBase + srcA[it] + k0n, &As[cur ^ 1][dstA[it]]);
            #pragma unroll
            for (int it = 0; it < 2; ++it)
                gload_lds16(bBase + srcB[it] + k0n, &Bs[cur ^ 1][dstB[it]]);
        }

        #pragma unroll
        for (int dc = 0; dc < 2; ++dc) {
            const int sw = ((dc * 4 + g) ^ (lc & 7)) << 3;
            bf16x8 af[4], bfr[2];
            #pragma unroll
            for (int i = 0; i < 4; ++i)
                af[i] = *(const bf16x8*)&As[cur][(wm * 64 + i * 16 + lc) * 64 + sw];
            #pragma unroll
            for (int j = 0; j < 2; ++j)
                bfr[j] = *(const bf16x8*)&Bs[cur][(wn * 32 + j * 16 + lc) * 64 + sw];

            #pragma unroll
            for (int i = 0; i < 4; ++i)
                #pragma unroll
                for (int j = 0; j < 2; ++j)
                    acc[i][j] = __builtin_amdgcn_mfma_f32_16x16x32_bf16(af[i], bfr[j], acc[i][j], 0, 0, 0);
        }
    }

    #pragma unroll
    for (int i = 0; i < 4; ++i) {
        const int mrow = m0 + wm * 64 + i * 16 + g * 4;
        #pragma unroll
        for (int j = 0; j < 2; ++j) {
            const int nc = n0 + wn * 32 + j * 16 + lc;
            #pragma unroll
            for (int r = 0; r < 4; ++r)
                cf[(size_t)(mrow + r) * 1024 + nc] = acc[i][j][r];
        }
    }
}

// ---------------------------------------------------------------------------
// Flash attention v3: 32x32x16 MFMA, S^T = K Q^T, O^T = V^T P^T.
// One 256-thr block per (b,h, q-tile 64). Wave (wj = w>>1, wq2 = w&1) owns
// q-half wq2 (32 rows), j-half wj (32 of each 64-tile).
// Fixed-shift softmax (|q|=|k|=1 after rmsnorm+scale => s in [-1,1]):
// p = exp(s), lane-local scalar lsum. P^T C-layout -> PV B-frags via
// half-wave shfl_xor(32). K/V^T staged async into XOR-swizzled LDS, dbuf.
// ---------------------------------------------------------------------------
__global__ __launch_bounds__(256) void flash_attn(const unsigned short* __restrict__ qb,
                                                  const unsigned short* __restrict__ kb,
                                                  const unsigned short* __restrict__ vt,
                                                  unsigned short* __restrict__ o)
{
    __shared__ __align__(16) unsigned short smem[2 * 64 * 128 + 2 * 128 * 64 + 128];
    unsigned short* KsB = smem;
    unsigned short* VsB = smem + 2 * 64 * 128;
    float* lscr = (float*)(smem + 2 * 64 * 128 + 2 * 128 * 64);
    float* scr  = (float*)smem;                    // epilogue scratch [64][129] f32

    const int tid  = threadIdx.x;
    const int lane = tid & 63;
    const int w    = tid >> 6;
    const int wj   = w >> 1;            // j-half
    const int wq2  = w & 1;             // q-half
    const int qcol = lane & 31;
    const int hi   = lane >> 5;         // half-wave

    const int bh = blockIdx.x;
    const int h  = bh & (H_ - 1);
    const int b  = bh >> 3;
    const int yy = blockIdx.y;
    const int qt = (yy & 1) ? (31 - (yy >> 1)) : (yy >> 1);
    const int q0 = qt * 64;

    const size_t bhbase  = (size_t)b * T_ * HD + (size_t)h * 128;   // q,k,o
    const size_t bhvbase = (size_t)bh * 128 * T_;                   // vt

    int mI[4];
    size_t srcKoff[4], srcVoff[4];
    #pragma unroll
    for (int it = 0; it < 4; ++it) {
        const int m = (w * 4 + it) * 64 + lane;
        mI[it] = m;
        const int jK = m >> 4, cK = (m & 15) ^ (jK & 15);
        srcKoff[it] = (size_t)jK * 1024 + cK * 8;
        const int dV = m >> 3, cV = (m & 7) ^ (dV & 7);
        srcVoff[it] = (size_t)dV * T_ + cV * 8;
    }
    const unsigned short* kgb = kb + bhbase;
    const unsigned short* vgb = vt + bhvbase;

    // Q as B-operand frags
    bf16x8 qf[8];
    {
        const unsigned short* qp = qb + bhbase + (size_t)(q0 + wq2 * 32 + qcol) * 1024 + hi * 8;
        #pragma unroll
        for (int ks = 0; ks < 8; ++ks)
            qf[ks] = *(const bf16x8*)(qp + ks * 16);
    }

    float lsum = 0.f;
    f32x16 otacc[4];
    #pragma unroll
    for (int dch = 0; dch < 4; ++dch)
        #pragma unroll
        for (int r = 0; r < 16; ++r) otacc[dch][r] = 0.f;

    #pragma unroll
    for (int it = 0; it < 4; ++it) {
        gload_lds16(kgb + srcKoff[it], &KsB[mI[it] * 8]);
        gload_lds16(vgb + srcVoff[it], &VsB[mI[it] * 8]);
    }

    for (int jt = 0; jt <= qt; ++jt) {
        const int cur = jt & 1;
        unsigned short* Ks = KsB + cur * (64 * 128);
        unsigned short* Vs = VsB + cur * (128 * 64);
        __syncthreads();

        if (jt < qt) {
            const size_t j0n = (size_t)(jt + 1) * 64;
            unsigned short* Kn = KsB + (cur ^ 1) * (64 * 128);
            unsigned short* Vn = VsB + (cur ^ 1) * (128 * 64);
            #pragma unroll
            for (int it = 0; it < 4; ++it) {
                gload_lds16(kgb + j0n * 1024 + srcKoff[it], &Kn[mI[it] * 8]);
                gload_lds16(vgb + j0n + srcVoff[it], &Vn[mI[it] * 8]);
            }
        }

        const bool dead = (jt == qt) && (wj > wq2);
        if (!dead) {
            f32x16 sacc;
            #pragma unroll
            for (int r = 0; r < 16; ++r) sacc[r] = 0.f;
            const int jrow = wj * 32 + qcol;
            #pragma unroll
            for (int ks = 0; ks < 8; ++ks) {
                const int c = ks * 2 + hi;
                bf16x8 af = *(const bf16x8*)&Ks[(jrow * 16 + (c ^ (lane & 15))) * 8];
                sacc = __builtin_amdgcn_mfma_f32_32x32x16_bf16(af, qf[ks], sacc, 0, 0, 0);
            }

            if (jt == qt && wj == wq2) {
                #pragma unroll
                for (int r = 0; r < 16; ++r) {
                    const int jl = (r & 3) + 8 * (r >> 2) + 4 * hi;
                    if (qcol < jl) sacc[r] = -1e30f;
                }
            }

            unsigned int dw[8];
            #pragma unroll
            for (int m2 = 0; m2 < 8; ++m2) {
                const float p0 = __expf(sacc[2 * m2]);
                const float p1 = __expf(sacc[2 * m2 + 1]);
                lsum += p0 + p1;
                dw[m2] = pk2bf(p0, p1);
            }
            unsigned int ex[8];
            #pragma unroll
            for (int m2 = 0; m2 < 8; ++m2)
                ex[m2] = (unsigned int)__shfl_xor((int)dw[m2], 32);

            #pragma unroll
            for (int ks2 = 0; ks2 < 2; ++ks2) {
                union { unsigned int u[4]; bf16x8 v; } pf;
                pf.u[0] = hi ? ex[4 * ks2 + 2] : dw[4 * ks2 + 0];
                pf.u[1] = hi ? ex[4 * ks2 + 3] : dw[4 * ks2 + 1];
                pf.u[2] = hi ? dw[4 * ks2 + 2] : ex[4 * ks2 + 0];
                pf.u[3] = hi ? dw[4 * ks2 + 3] : ex[4 * ks2 + 1];
                #pragma unroll
                for (int dch = 0; dch < 4; ++dch) {
                    const int c = wj * 4 + ks2 * 2 + hi;
                    const int drow = dch * 32 + qcol;
                    bf16x8 af = *(const bf16x8*)&Vs[(drow * 8 + (c ^ (lane & 7))) * 8];
                    otacc[dch] = __builtin_amdgcn_mfma_f32_32x32x16_bf16(af, pf.v, otacc[dch], 0, 0, 0);
                }
            }
        }
    }

    // epilogue: merge wj pairs via LDS, write O bf16
    lsum += __shfl_xor(lsum, 32);
    __syncthreads();

    if (wj == 1) {
        float* s0 = scr + (size_t)(wq2 * 32 + qcol) * 129;
        #pragma unroll
        for (int dch = 0; dch < 4; ++dch)
            #pragma unroll
            for (int r = 0; r < 16; ++r)
                s0[dch * 32 + (r & 3) + 8 * (r >> 2) + 4 * hi] = otacc[dch][r];
        if (hi == 0) lscr[wq2 * 32 + qcol] = lsum;
    }
    __syncthreads();
    if (wj == 0) {
        const float l = lsum + lscr[wq2 * 32 + qcol];
        const float inv = 1.0f / l;
        const float* s0 = scr + (size_t)(wq2 * 32 + qcol) * 129;
        unsigned short* op = o + bhbase + (size_t)(q0 + wq2 * 32 + qcol) * 1024;
        #pragma unroll
        for (int dch = 0; dch < 4; ++dch) {
            #pragma unroll
            for (int k4 = 0; k4 < 4; ++k4) {
                const int d0 = dch * 32 + 8 * k4 + 4 * hi;
                const float f0 = (otacc[dch][4 * k4 + 0] + s0[d0 + 0]) * inv;
                const float f1 = (otacc[dch][4 * k4 + 1] + s0[d0 + 1]) * inv;
                const float f2 = (otacc[dch][4 * k4 + 2] + s0[d0 + 2]) * inv;
                const float f3 = (otacc[dch][4 * k4 + 3] + s0[d0 + 3]) * inv;
                uint2 val;
                val.x = pk2bf(f0, f1);
                val.y = pk2bf(f2, f3);
                *(uint2*)(op + d0) = val;
            }
        }
    }
}

// ---------------------------------------------------------------------------
extern "C" void kernel_launch(void* const* d_in, const int* in_sizes, int n_in,
                              void* d_out, int out_size, void* d_ws, size_t ws_size,
                              hipStream_t stream)
{
    const float* x  = (const float*)d_in[0];
    const float* wq = (const float*)d_in[1];
    const float* wk = (const float*)d_in[2];
    const float* wv = (const float*)d_in[3];
    const float* wo = (const float*)d_in[4];
    float* out = (float*)d_out;

    const size_t SZ = (size_t)NROW * HD;               // 4M elements
    unsigned short* qb    = (unsigned short*)d_ws;     // 8 MB
    unsigned short* kb    = qb + SZ;                   // 8 MB
    unsigned short* vt    = kb + SZ;                   // 8 MB [(b,h),d,t]
    unsigned short* ob    = vt + SZ;                   // 8 MB
    unsigned short* xb    = ob + SZ;                   // 8 MB
    unsigned short* wqkvT = xb + SZ;                   // 6 MB [3072][1024]
    unsigned short* woT   = wqkvT + 3 * 1024 * 1024;   // 2 MB

    // prologue: x cast + 4 weight transposes, one launch
    prep<<<dim3(32, 32, 5), 256, 0, stream>>>(x, wq, wk, wv, wo, xb, wqkvT, woT);

    // fused QKV projection (+ RMSNorm/RoPE on q,k; V written transposed)
    gemm_qkv<<<dim3(24, 32), 256, 0, stream>>>(xb, wqkvT, qb, kb, vt);

    flash_attn<<<dim3(B_ * H_, 32), 256, 0, stream>>>(qb, kb, vt, ob);

    // output projection, 128x64 tiles -> 512 blocks
    gemm_out<<<dim3(16, 32), 256, 0, stream>>>(ob, woT, out);
}